// Round 16
// baseline (194.894 us; speedup 1.0000x reference)
//
#include <hip/hip_runtime.h>
#include <math.h>

#define N_NODES 50000
#define F_IN    128
#define HIDC    64
#define HEADS   4
#define C1      (HEADS*HIDC)   // 256
#define F_OUT   128
#define NE      800000
#define NET     (NE + N_NODES) // 850000 edges incl self-loops
#define NEG_SLOPE 0.2f

#define NPB   49               // nodes per bucket
#define NBUCK 1021             // ceil(N_NODES / NPB)
#define BPAD  16               // counter padding (ints): 1 counter per 64B line
#define K4CAP 2048             // build_csr LDS staging cap (mean 833)
#define SCHUNK 8192            // edges per scatter block

typedef unsigned short ushort_t;
typedef signed char    schar_t;
typedef __attribute__((ext_vector_type(8))) short bf16x8;
typedef __attribute__((ext_vector_type(8))) unsigned short us8;
typedef __attribute__((ext_vector_type(4))) float f32x4;

__device__ __forceinline__ float b2f(ushort_t x) {
  return __uint_as_float(((unsigned int)x) << 16);
}
__device__ __forceinline__ ushort_t f2bf(float f) {  // RNE, no NaN expected
  unsigned int u = __float_as_uint(f);
  return (ushort_t)((u + 0x7fffu + ((u >> 16) & 1u)) >> 16);
}

// int8 x16 decode: wsc = w * scale folded; denominator uses raw w.
__device__ __forceinline__ void fma16q(float wsc, uint4 vv, float* a) {
  int p0 = (int)vv.x, p1 = (int)vv.y, p2 = (int)vv.z, p3 = (int)vv.w;
  a[0]  = fmaf(wsc, (float)(schar_t)(p0),       a[0]);
  a[1]  = fmaf(wsc, (float)(schar_t)(p0 >> 8),  a[1]);
  a[2]  = fmaf(wsc, (float)(schar_t)(p0 >> 16), a[2]);
  a[3]  = fmaf(wsc, (float)(p0 >> 24),          a[3]);
  a[4]  = fmaf(wsc, (float)(schar_t)(p1),       a[4]);
  a[5]  = fmaf(wsc, (float)(schar_t)(p1 >> 8),  a[5]);
  a[6]  = fmaf(wsc, (float)(schar_t)(p1 >> 16), a[6]);
  a[7]  = fmaf(wsc, (float)(p1 >> 24),          a[7]);
  a[8]  = fmaf(wsc, (float)(schar_t)(p2),       a[8]);
  a[9]  = fmaf(wsc, (float)(schar_t)(p2 >> 8),  a[9]);
  a[10] = fmaf(wsc, (float)(schar_t)(p2 >> 16), a[10]);
  a[11] = fmaf(wsc, (float)(p2 >> 24),          a[11]);
  a[12] = fmaf(wsc, (float)(schar_t)(p3),       a[12]);
  a[13] = fmaf(wsc, (float)(schar_t)(p3 >> 8),  a[13]);
  a[14] = fmaf(wsc, (float)(schar_t)(p3 >> 16), a[14]);
  a[15] = fmaf(wsc, (float)(p3 >> 24),          a[15]);
}

// ---------------- bucketed CSR build ----------------

__global__ __launch_bounds__(256) void bucket_count(const int* __restrict__ ei,
                                                    int* __restrict__ bcnt) {
  __shared__ int hist[NBUCK];
  for (int i = threadIdx.x; i < NBUCK; i += 256) hist[i] = 0;
  __syncthreads();
  int stride = gridDim.x * 256;
  for (int e = blockIdx.x * 256 + threadIdx.x; e < NET; e += stride) {
    int d = (e < NE) ? ei[NE + e] : (e - NE);
    atomicAdd(&hist[d / NPB], 1);
  }
  __syncthreads();
  for (int i = threadIdx.x; i < NBUCK; i += 256)
    if (hist[i]) atomicAdd(&bcnt[i * BPAD], hist[i]);
}

__global__ __launch_bounds__(1024) void scan_buckets(const int* __restrict__ bcnt,
                                                     int* __restrict__ boff) {
  __shared__ int sh[1024];
  int t = threadIdx.x;
  sh[t] = (t < NBUCK) ? bcnt[t * BPAD] : 0;
  __syncthreads();
#pragma unroll
  for (int off = 1; off < 1024; off <<= 1) {
    int u = (t >= off) ? sh[t - off] : 0;
    __syncthreads();
    sh[t] += u;
    __syncthreads();
  }
  if (t < NBUCK) boff[t + 1] = sh[t];
  if (t == 0) boff[0] = 0;
}

// Block-owned contiguous runs: every 64B pairs-line written by ONE block.
__global__ __launch_bounds__(1024) void bucket_scatter_blocked(const int* __restrict__ ei,
                                                               const int* __restrict__ boff,
                                                               int* __restrict__ bfill,
                                                               int2* __restrict__ pairs) {
  __shared__ int hist[NBUCK];
  __shared__ int gbase[NBUCK];
  __shared__ int fill[NBUCK];
  int c0 = blockIdx.x * SCHUNK;
  int cend = min(c0 + SCHUNK, NET);
  for (int i = threadIdx.x; i < NBUCK; i += 1024) { hist[i] = 0; fill[i] = 0; }
  __syncthreads();
  for (int e = c0 + threadIdx.x; e < cend; e += 1024) {
    int d = (e < NE) ? ei[NE + e] : (e - NE);
    atomicAdd(&hist[d / NPB], 1);
  }
  __syncthreads();
  for (int i = threadIdx.x; i < NBUCK; i += 1024)
    if (hist[i]) gbase[i] = boff[i] + atomicAdd(&bfill[i * BPAD], hist[i]);
  __syncthreads();
  for (int e = c0 + threadIdx.x; e < cend; e += 1024) {
    int s, d;
    if (e < NE) { s = ei[e]; d = ei[NE + e]; }
    else        { s = e - NE; d = s; }
    int b = d / NPB;
    int lpos = atomicAdd(&fill[b], 1);
    pairs[gbase[b] + lpos] = make_int2(s, d);
  }
}

__global__ __launch_bounds__(256) void build_csr(const int2* __restrict__ pairs,
                                                 const int* __restrict__ boff,
                                                 int* __restrict__ rowptr,
                                                 int* __restrict__ colsrc) {
  __shared__ int cnt[NPB];
  __shared__ int loc[NPB + 1];
  __shared__ int2 buf[K4CAP];
  int b = blockIdx.x, t = threadIdx.x;
  int p0 = boff[b], p1 = boff[b + 1];
  int m = p1 - p0;
  int n0 = b * NPB;
  int nn = min(NPB, N_NODES - n0);
  for (int i = t; i < NPB; i += 256) cnt[i] = 0;
  __syncthreads();
  bool inlds = (m <= K4CAP);
  for (int i = t; i < m; i += 256) {
    int2 p = pairs[p0 + i];
    if (inlds) buf[i] = p;
    atomicAdd(&cnt[p.y - n0], 1);
  }
  __syncthreads();
  if (t == 0) {
    int run = 0;
#pragma unroll 1
    for (int j = 0; j < nn; ++j) { loc[j] = run; run += cnt[j]; }
    loc[nn] = run;
  }
  __syncthreads();
  for (int j = t; j < nn; j += 256) rowptr[n0 + j] = p0 + loc[j];
  if (t == 0 && n0 + nn == N_NODES) rowptr[N_NODES] = NET;
  for (int i = t; i < NPB; i += 256) cnt[i] = 0;
  __syncthreads();
  for (int i = t; i < m; i += 256) {
    int2 p = inlds ? buf[i] : pairs[p0 + i];
    int j = p.y - n0;
    int pos = atomicAdd(&cnt[j], 1);
    colsrc[p0 + loc[j] + pos] = p.x;
  }
}

// ---------------- setup: both weight transposes in one kernel ----------------

__global__ void transpose_both(const float* __restrict__ W1, ushort_t* __restrict__ W1t,
                               const float* __restrict__ W2, ushort_t* __restrict__ W2t) {
  int idx = blockIdx.x * blockDim.x + threadIdx.x;
  if (idx < F_IN * C1) {
    int k = idx / C1, n = idx - k * C1;
    W1t[(size_t)n * F_IN + k] = f2bf(W1[idx]);
  } else {
    int j = idx - F_IN * C1;
    if (j < C1 * F_OUT) {
      int k = j / F_OUT, n = j - k * F_OUT;
      W2t[(size_t)n * C1 + k] = f2bf(W2[j]);
    }
  }
}

// ---------------- MFMA bf16 GEMM with fused AL-logit epilogue ----------------
// CT=schar_t: int8 C + per-64ch scale (stride SCST/node). CT=ushort_t: bf16 C.

#define BKS 64
#define LDT 72

__device__ __forceinline__ us8 stage8(const ushort_t* p) { return *(const us8*)p; }
__device__ __forceinline__ us8 stage8(const float* p) {
  float4 f0 = *(const float4*)p;
  float4 f1 = *(const float4*)(p + 4);
  us8 o;
  o[0] = f2bf(f0.x); o[1] = f2bf(f0.y); o[2] = f2bf(f0.z); o[3] = f2bf(f0.w);
  o[4] = f2bf(f1.x); o[5] = f2bf(f1.y); o[6] = f2bf(f1.z); o[7] = f2bf(f1.w);
  return o;
}

template<int K, int NCOL, int AL_MODE, int SCST, typename AT, typename CT>
__global__ __launch_bounds__(256) void gemm_mfma(const AT* __restrict__ A,
                                                 const ushort_t* __restrict__ Bt,
                                                 CT* __restrict__ C,
                                                 float* __restrict__ scales,
                                                 const float* __restrict__ a_s,
                                                 const float* __restrict__ a_d,
                                                 float* __restrict__ als,
                                                 float* __restrict__ ald) {
  __shared__ __align__(16) char smem[2 * 128 * LDT * 2];
  ushort_t (*Asl)[LDT] = (ushort_t(*)[LDT])smem;
  ushort_t (*Bsl)[LDT] = (ushort_t(*)[LDT])(smem + 128 * LDT * 2);

  const int tid = threadIdx.x;
  const int lane = tid & 63;
  const int wave = tid >> 6;
  const int wr = wave >> 1, wc = wave & 1;
  const int row0 = blockIdx.y * 128;
  const int col0 = blockIdx.x * 128;
  const int l15 = lane & 15, l4 = lane >> 4;

  f32x4 acc[4][4] = {};

  for (int k0 = 0; k0 < K; k0 += BKS) {
#pragma unroll
    for (int i = 0; i < 4; ++i) {
      int seg = tid + i * 256;
      int row = seg >> 3, kq = (seg & 7) * 8;
      int arow = row0 + row;
      us8 v = {0, 0, 0, 0, 0, 0, 0, 0};
      if (arow < N_NODES) v = stage8(&A[(size_t)arow * K + k0 + kq]);
      *(us8*)&Asl[row][kq] = v;
    }
#pragma unroll
    for (int i = 0; i < 4; ++i) {
      int seg = tid + i * 256;
      int row = seg >> 3, kq = (seg & 7) * 8;
      us8 v = *(const us8*)&Bt[(size_t)(col0 + row) * K + k0 + kq];
      *(us8*)&Bsl[row][kq] = v;
    }
    __syncthreads();
#pragma unroll
    for (int kk = 0; kk < BKS; kk += 32) {
      bf16x8 af[4], bfr[4];
#pragma unroll
      for (int mi = 0; mi < 4; ++mi)
        af[mi] = *(const bf16x8*)&Asl[wr * 64 + mi * 16 + l15][kk + l4 * 8];
#pragma unroll
      for (int ni = 0; ni < 4; ++ni)
        bfr[ni] = *(const bf16x8*)&Bsl[wc * 64 + ni * 16 + l15][kk + l4 * 8];
#pragma unroll
      for (int mi = 0; mi < 4; ++mi)
#pragma unroll
        for (int ni = 0; ni < 4; ++ni)
          acc[mi][ni] = __builtin_amdgcn_mfma_f32_16x16x32_bf16(af[mi], bfr[ni], acc[mi][ni], 0, 0, 0);
    }
    __syncthreads();
  }

  // ---- fused attention-logit dots ----
  {
    const int albase = (AL_MODE == 1 ? col0 : 0) + wc * 64;
    float asv[4], adv[4];
#pragma unroll
    for (int ni = 0; ni < 4; ++ni) {
      asv[ni] = a_s[albase + ni * 16 + l15];
      adv[ni] = a_d[albase + ni * 16 + l15];
    }
#pragma unroll
    for (int mi = 0; mi < 4; ++mi) {
      float ps[4], pd[4];
#pragma unroll
      for (int r = 0; r < 4; ++r) {
        ps[r] = acc[mi][0][r] * asv[0] + acc[mi][1][r] * asv[1] +
                acc[mi][2][r] * asv[2] + acc[mi][3][r] * asv[3];
        pd[r] = acc[mi][0][r] * adv[0] + acc[mi][1][r] * adv[1] +
                acc[mi][2][r] * adv[2] + acc[mi][3][r] * adv[3];
      }
#pragma unroll
      for (int m = 1; m < 16; m <<= 1) {
#pragma unroll
        for (int r = 0; r < 4; ++r) {
          ps[r] += __shfl_xor(ps[r], m, 64);
          pd[r] += __shfl_xor(pd[r], m, 64);
        }
      }
      if (l15 == 0) {
#pragma unroll
        for (int r = 0; r < 4; ++r) {
          int row = row0 + wr * 64 + mi * 16 + l4 * 4 + r;
          if (row < N_NODES) {
            if (AL_MODE == 1) {
              int h = albase >> 6;
              als[row * 4 + h] = ps[r];
              ald[row * 4 + h] = pd[r];
            } else {
              atomicAdd(&als[row], ps[r]);
              atomicAdd(&ald[row], pd[r]);
            }
          }
        }
      }
    }
  }

  // ---- C epilogue: acc -> LDS bf16 bounce -> global (int8+scale or bf16) ----
  {
    ushort_t (*Ep)[136] = (ushort_t(*)[136])smem;
#pragma unroll
    for (int mi = 0; mi < 4; ++mi)
#pragma unroll
      for (int ni = 0; ni < 4; ++ni)
#pragma unroll
        for (int r = 0; r < 4; ++r)
          Ep[wr * 64 + mi * 16 + l4 * 4 + r][wc * 64 + ni * 16 + l15] = f2bf(acc[mi][ni][r]);
    __syncthreads();
    int row = tid >> 1, half = tid & 1;
    int grow = row0 + row;
    if (grow < N_NODES) {
      if constexpr (sizeof(CT) == 1) {
        float vals[64];
        float amax = 0.f;
#pragma unroll
        for (int i = 0; i < 8; ++i) {
          us8 v = *(const us8*)&Ep[row][half * 64 + i * 8];
#pragma unroll
          for (int j = 0; j < 8; ++j) {
            float f = b2f((ushort_t)v[j]);
            vals[i * 8 + j] = f;
            amax = fmaxf(amax, fabsf(f));
          }
        }
        float inv = amax > 0.f ? 127.f / amax : 0.f;
        scales[grow * SCST + (col0 >> 6) + half] = amax * (1.f / 127.f);
        schar_t ob[64];
#pragma unroll
        for (int i = 0; i < 64; ++i)
          ob[i] = (schar_t)(int)rintf(vals[i] * inv);
#pragma unroll
        for (int i = 0; i < 4; ++i)
          *(us8*)&C[(size_t)grow * NCOL + col0 + half * 64 + i * 16] =
              *(const us8*)&ob[i * 16];
      } else {
#pragma unroll
        for (int i = 0; i < 8; ++i)
          *(us8*)&C[(size_t)grow * NCOL + col0 + half * 64 + i * 8] =
              *(const us8*)&Ep[row][half * 64 + i * 8];
      }
    }
  }
}

// ---------------- fused softmax + gather aggregation (all int8) ----------------

// layer1: quarter-wave (16 lanes x 16B) per edge; 4 edges/wave; unroll 4 -> 16 in flight.
__global__ __launch_bounds__(256) void agg1(const int* __restrict__ rowptr,
                                            const int* __restrict__ colsrc,
                                            const schar_t* __restrict__ Hq,
                                            const float* __restrict__ Sc,
                                            const float* __restrict__ als,
                                            const float* __restrict__ ald,
                                            const float* __restrict__ b1,
                                            ushort_t* __restrict__ X2b) {
  int wave = threadIdx.x >> 6, lane = threadIdx.x & 63;
  int n = blockIdx.x * 4 + wave;
  if (n >= N_NODES) return;
  int grp = lane >> 4, li = lane & 15;
  int h = li >> 2;                      // 16 channels/lane: c = li*16, head = c/64
  float ad = ald[n * 4 + h];
  int beg = rowptr[n], end = rowptr[n + 1];
  float a[16] = {};
  float s = 0.f;
  int i = beg + grp;
  for (; i + 12 < end; i += 16) {
    int s0 = colsrc[i], s1 = colsrc[i + 4], s2 = colsrc[i + 8], s3 = colsrc[i + 12];
    float sc0 = als[s0 * 4 + h] + ad;
    float sc1 = als[s1 * 4 + h] + ad;
    float sc2 = als[s2 * 4 + h] + ad;
    float sc3 = als[s3 * 4 + h] + ad;
    float q0 = Sc[s0 * 4 + h], q1 = Sc[s1 * 4 + h], q2 = Sc[s2 * 4 + h], q3 = Sc[s3 * 4 + h];
    uint4 v0 = *(const uint4*)&Hq[(size_t)s0 * C1 + li * 16];
    uint4 v1 = *(const uint4*)&Hq[(size_t)s1 * C1 + li * 16];
    uint4 v2 = *(const uint4*)&Hq[(size_t)s2 * C1 + li * 16];
    uint4 v3 = *(const uint4*)&Hq[(size_t)s3 * C1 + li * 16];
    sc0 = sc0 > 0.f ? sc0 : NEG_SLOPE * sc0;
    sc1 = sc1 > 0.f ? sc1 : NEG_SLOPE * sc1;
    sc2 = sc2 > 0.f ? sc2 : NEG_SLOPE * sc2;
    sc3 = sc3 > 0.f ? sc3 : NEG_SLOPE * sc3;
    float w0 = __expf(sc0), w1 = __expf(sc1), w2 = __expf(sc2), w3 = __expf(sc3);
    s += (w0 + w1) + (w2 + w3);
    fma16q(w0 * q0, v0, a); fma16q(w1 * q1, v1, a);
    fma16q(w2 * q2, v2, a); fma16q(w3 * q3, v3, a);
  }
  for (; i + 4 < end; i += 8) {
    int s0 = colsrc[i], s1 = colsrc[i + 4];
    float sc0 = als[s0 * 4 + h] + ad;
    float sc1 = als[s1 * 4 + h] + ad;
    float q0 = Sc[s0 * 4 + h], q1 = Sc[s1 * 4 + h];
    uint4 v0 = *(const uint4*)&Hq[(size_t)s0 * C1 + li * 16];
    uint4 v1 = *(const uint4*)&Hq[(size_t)s1 * C1 + li * 16];
    sc0 = sc0 > 0.f ? sc0 : NEG_SLOPE * sc0;
    sc1 = sc1 > 0.f ? sc1 : NEG_SLOPE * sc1;
    float w0 = __expf(sc0), w1 = __expf(sc1);
    s += w0 + w1;
    fma16q(w0 * q0, v0, a); fma16q(w1 * q1, v1, a);
  }
  for (; i < end; i += 4) {
    int s0 = colsrc[i];
    float sc0 = als[s0 * 4 + h] + ad;
    float q0 = Sc[s0 * 4 + h];
    uint4 v0 = *(const uint4*)&Hq[(size_t)s0 * C1 + li * 16];
    sc0 = sc0 > 0.f ? sc0 : NEG_SLOPE * sc0;
    float w0 = __expf(sc0);
    s += w0;
    fma16q(w0 * q0, v0, a);
  }
#pragma unroll
  for (int j = 0; j < 16; ++j) a[j] += __shfl_xor(a[j], 16, 64);
#pragma unroll
  for (int j = 0; j < 16; ++j) a[j] += __shfl_xor(a[j], 32, 64);
  s += __shfl_xor(s, 16, 64);
  s += __shfl_xor(s, 32, 64);
  if (lane < 16) {
    float si = 1.f / s;
    int c = li * 16;
    ushort_t o[16];
#pragma unroll
    for (int j = 0; j < 16; ++j)
      o[j] = f2bf(fmaxf(a[j] * si + b1[c + j], 0.f));
    *(us8*)&X2b[(size_t)n * C1 + c] = *(const us8*)&o[0];
    *(us8*)&X2b[(size_t)n * C1 + c + 8] = *(const us8*)&o[8];
  }
}

// layer2: eighth-wave (8 lanes x 16B) per edge; 8 edges/wave; unroll 2 -> 16 in flight.
__global__ __launch_bounds__(256) void agg2(const int* __restrict__ rowptr,
                                            const int* __restrict__ colsrc,
                                            const schar_t* __restrict__ Hq,
                                            const float* __restrict__ Sc,
                                            const float* __restrict__ als,
                                            const float* __restrict__ ald,
                                            const float* __restrict__ b2,
                                            float* __restrict__ out) {
  int wave = threadIdx.x >> 6, lane = threadIdx.x & 63;
  int n = blockIdx.x * 4 + wave;
  if (n >= N_NODES) return;
  int grp = lane >> 3, li = lane & 7;
  int hb = li >> 2;                     // 16 ch/lane: c = li*16, 64-block = c/64
  float ad = ald[n];
  int beg = rowptr[n], end = rowptr[n + 1];
  float a[16] = {};
  float s = 0.f;
  int i = beg + grp;
  for (; i + 8 < end; i += 16) {
    int s0 = colsrc[i], s1 = colsrc[i + 8];
    float sc0 = als[s0] + ad;
    float sc1 = als[s1] + ad;
    float q0 = Sc[s0 * 2 + hb], q1 = Sc[s1 * 2 + hb];
    uint4 v0 = *(const uint4*)&Hq[(size_t)s0 * F_OUT + li * 16];
    uint4 v1 = *(const uint4*)&Hq[(size_t)s1 * F_OUT + li * 16];
    sc0 = sc0 > 0.f ? sc0 : NEG_SLOPE * sc0;
    sc1 = sc1 > 0.f ? sc1 : NEG_SLOPE * sc1;
    float w0 = __expf(sc0), w1 = __expf(sc1);
    s += w0 + w1;
    fma16q(w0 * q0, v0, a); fma16q(w1 * q1, v1, a);
  }
  for (; i < end; i += 8) {
    int s0 = colsrc[i];
    float sc0 = als[s0] + ad;
    float q0 = Sc[s0 * 2 + hb];
    uint4 v0 = *(const uint4*)&Hq[(size_t)s0 * F_OUT + li * 16];
    sc0 = sc0 > 0.f ? sc0 : NEG_SLOPE * sc0;
    float w0 = __expf(sc0);
    s += w0;
    fma16q(w0 * q0, v0, a);
  }
#pragma unroll
  for (int j = 0; j < 16; ++j) a[j] += __shfl_xor(a[j], 8, 64);
#pragma unroll
  for (int j = 0; j < 16; ++j) a[j] += __shfl_xor(a[j], 16, 64);
#pragma unroll
  for (int j = 0; j < 16; ++j) a[j] += __shfl_xor(a[j], 32, 64);
  s += __shfl_xor(s, 8, 64);
  s += __shfl_xor(s, 16, 64);
  s += __shfl_xor(s, 32, 64);
  if (lane < 8) {
    float si = 1.f / s;
    int c = li * 16;
#pragma unroll
    for (int j = 0; j < 4; ++j) {
      float4 o;
      o.x = a[j * 4 + 0] * si + b2[c + j * 4 + 0];
      o.y = a[j * 4 + 1] * si + b2[c + j * 4 + 1];
      o.z = a[j * 4 + 2] * si + b2[c + j * 4 + 2];
      o.w = a[j * 4 + 3] * si + b2[c + j * 4 + 3];
      *(float4*)&out[(size_t)n * F_OUT + c + j * 4] = o;
    }
  }
}

// ---------------- launch ----------------

extern "C" void kernel_launch(void* const* d_in, const int* in_sizes, int n_in,
                              void* d_out, int out_size, void* d_ws, size_t ws_size,
                              hipStream_t stream) {
  const float* X   = (const float*)d_in[0];
  const int*   EI  = (const int*)d_in[1];
  const float* W1  = (const float*)d_in[2];
  const float* a1s = (const float*)d_in[3];
  const float* a1d = (const float*)d_in[4];
  const float* b1  = (const float*)d_in[5];
  const float* W2  = (const float*)d_in[6];
  const float* a2s = (const float*)d_in[7];
  const float* a2d = (const float*)d_in[8];
  const float* b2  = (const float*)d_in[9];
  float* out = (float*)d_out;

  char* ws = (char*)d_ws;
  size_t off = 0;
  auto alloc = [&](size_t bytes) -> void* {
    void* p = ws + off;
    off += (bytes + 255) & ~(size_t)255;
    return p;
  };
  // zero-init block first (single memset)
  int* bcnt       = (int*)alloc((size_t)NBUCK * BPAD * 4);
  int* bfill      = (int*)alloc((size_t)NBUCK * BPAD * 4);
  float* ALS2     = (float*)alloc((size_t)N_NODES * 4);
  float* ALD2     = (float*)alloc((size_t)N_NODES * 4);
  size_t zero_span = off;
  int* boff       = (int*)alloc((size_t)(NBUCK + 1) * 4);
  int* rowptr     = (int*)alloc((size_t)(N_NODES + 1) * 4);
  int* colsrc     = (int*)alloc((size_t)NET * 4);
  int2* pairs     = (int2*)alloc((size_t)NET * 8);
  ushort_t* W1t   = (ushort_t*)alloc((size_t)C1 * F_IN * 2);
  ushort_t* W2t   = (ushort_t*)alloc((size_t)F_OUT * C1 * 2);
  schar_t* H1q    = (schar_t*)alloc((size_t)N_NODES * C1);        // 12.8MB int8
  float* SC1      = (float*)alloc((size_t)N_NODES * HEADS * 4);
  float* SC2      = (float*)alloc((size_t)N_NODES * 2 * 4);
  float* ALS1     = (float*)alloc((size_t)N_NODES * HEADS * 4);
  float* ALD1     = (float*)alloc((size_t)N_NODES * HEADS * 4);
  ushort_t* X2b   = (ushort_t*)alloc((size_t)N_NODES * C1 * 2);
  schar_t* H2q = H1q;  // H1 dead after agg1; layer-2 int8 table 6.4MB <= 12.8MB

  hipMemsetAsync(ws, 0, zero_span, stream);

  // bucketed CSR build (block-owned scatter runs)
  bucket_count<<<128, 256, 0, stream>>>(EI, bcnt);
  scan_buckets<<<1, 1024, 0, stream>>>(bcnt, boff);
  bucket_scatter_blocked<<<(NET + SCHUNK - 1) / SCHUNK, 1024, 0, stream>>>(EI, boff, bfill, pairs);
  build_csr<<<NBUCK, 256, 0, stream>>>(pairs, boff, rowptr, colsrc);

  // weight transposes (bf16), single launch
  transpose_both<<<(F_IN * C1 + C1 * F_OUT + 255) / 256, 256, 0, stream>>>(W1, W1t, W2, W2t);

  // layer 1 (A = fp32 X converted in staging; C = int8 + 4 scales/node)
  {
    dim3 grid(C1 / 128, (N_NODES + 127) / 128);
    gemm_mfma<F_IN, C1, 1, 4, float, schar_t><<<grid, 256, 0, stream>>>(
        X, W1t, H1q, SC1, a1s, a1d, ALS1, ALD1);
  }
  agg1<<<(N_NODES + 3) / 4, 256, 0, stream>>>(rowptr, colsrc, H1q, SC1, ALS1, ALD1, b1, X2b);

  // layer 2 (A = bf16 X2; C = int8 + 2 scales/node)
  {
    dim3 grid(F_OUT / 128, (N_NODES + 127) / 128);
    gemm_mfma<C1, F_OUT, 2, 2, ushort_t, schar_t><<<grid, 256, 0, stream>>>(
        X2b, W2t, H2q, SC2, a2s, a2d, ALS2, ALD2);
  }
  agg2<<<(N_NODES + 3) / 4, 256, 0, stream>>>(rowptr, colsrc, H2q, SC2, ALS2, ALD2, b2, out);
}

// Round 17
// 170.787 us; speedup vs baseline: 1.1412x; 1.1412x over previous
//
#include <hip/hip_runtime.h>
#include <math.h>

#define N_NODES 50000
#define F_IN    128
#define HIDC    64
#define HEADS   4
#define C1      (HEADS*HIDC)   // 256
#define F_OUT   128
#define NE      800000
#define NET     (NE + N_NODES) // 850000 edges incl self-loops
#define NEG_SLOPE 0.2f

#define NPB   49               // nodes per bucket
#define NBUCK 1021             // ceil(N_NODES / NPB)
#define BPAD  16               // counter padding (ints): 1 counter per 64B line
#define K4CAP 2048             // build_csr LDS staging cap (mean 833)
#define SCHUNK 8192            // edges per scatter block

typedef unsigned short ushort_t;
typedef signed char    schar_t;
typedef __attribute__((ext_vector_type(8))) short bf16x8;
typedef __attribute__((ext_vector_type(8))) unsigned short us8;
typedef __attribute__((ext_vector_type(4))) float f32x4;

__device__ __forceinline__ float b2f(ushort_t x) {
  return __uint_as_float(((unsigned int)x) << 16);
}
__device__ __forceinline__ ushort_t f2bf(float f) {  // RNE, no NaN expected
  unsigned int u = __float_as_uint(f);
  return (ushort_t)((u + 0x7fffu + ((u >> 16) & 1u)) >> 16);
}

// int8 x8 decode: wsc = w * scale folded; denominator uses raw w.
__device__ __forceinline__ void fma8q(float wsc, uint2 vv, float* a) {
  int x = (int)vv.x, y = (int)vv.y;
  a[0] = fmaf(wsc, (float)(schar_t)(x),        a[0]);
  a[1] = fmaf(wsc, (float)(schar_t)(x >> 8),   a[1]);
  a[2] = fmaf(wsc, (float)(schar_t)(x >> 16),  a[2]);
  a[3] = fmaf(wsc, (float)(x >> 24),           a[3]);
  a[4] = fmaf(wsc, (float)(schar_t)(y),        a[4]);
  a[5] = fmaf(wsc, (float)(schar_t)(y >> 8),   a[5]);
  a[6] = fmaf(wsc, (float)(schar_t)(y >> 16),  a[6]);
  a[7] = fmaf(wsc, (float)(y >> 24),           a[7]);
}

// ---------------- bucketed CSR build ----------------

__global__ __launch_bounds__(256) void bucket_count(const int* __restrict__ ei,
                                                    int* __restrict__ bcnt) {
  __shared__ int hist[NBUCK];
  for (int i = threadIdx.x; i < NBUCK; i += 256) hist[i] = 0;
  __syncthreads();
  int stride = gridDim.x * 256;
  for (int e = blockIdx.x * 256 + threadIdx.x; e < NET; e += stride) {
    int d = (e < NE) ? ei[NE + e] : (e - NE);
    atomicAdd(&hist[d / NPB], 1);
  }
  __syncthreads();
  for (int i = threadIdx.x; i < NBUCK; i += 256)
    if (hist[i]) atomicAdd(&bcnt[i * BPAD], hist[i]);
}

__global__ __launch_bounds__(1024) void scan_buckets(const int* __restrict__ bcnt,
                                                     int* __restrict__ boff) {
  __shared__ int sh[1024];
  int t = threadIdx.x;
  sh[t] = (t < NBUCK) ? bcnt[t * BPAD] : 0;
  __syncthreads();
#pragma unroll
  for (int off = 1; off < 1024; off <<= 1) {
    int u = (t >= off) ? sh[t - off] : 0;
    __syncthreads();
    sh[t] += u;
    __syncthreads();
  }
  if (t < NBUCK) boff[t + 1] = sh[t];
  if (t == 0) boff[0] = 0;
}

// Block-owned contiguous runs: every 64B pairs-line written by ONE block.
__global__ __launch_bounds__(1024) void bucket_scatter_blocked(const int* __restrict__ ei,
                                                               const int* __restrict__ boff,
                                                               int* __restrict__ bfill,
                                                               int2* __restrict__ pairs) {
  __shared__ int hist[NBUCK];
  __shared__ int gbase[NBUCK];
  __shared__ int fill[NBUCK];
  int c0 = blockIdx.x * SCHUNK;
  int cend = min(c0 + SCHUNK, NET);
  for (int i = threadIdx.x; i < NBUCK; i += 1024) { hist[i] = 0; fill[i] = 0; }
  __syncthreads();
  for (int e = c0 + threadIdx.x; e < cend; e += 1024) {
    int d = (e < NE) ? ei[NE + e] : (e - NE);
    atomicAdd(&hist[d / NPB], 1);
  }
  __syncthreads();
  for (int i = threadIdx.x; i < NBUCK; i += 1024)
    if (hist[i]) gbase[i] = boff[i] + atomicAdd(&bfill[i * BPAD], hist[i]);
  __syncthreads();
  for (int e = c0 + threadIdx.x; e < cend; e += 1024) {
    int s, d;
    if (e < NE) { s = ei[e]; d = ei[NE + e]; }
    else        { s = e - NE; d = s; }
    int b = d / NPB;
    int lpos = atomicAdd(&fill[b], 1);
    pairs[gbase[b] + lpos] = make_int2(s, d);
  }
}

__global__ __launch_bounds__(256) void build_csr(const int2* __restrict__ pairs,
                                                 const int* __restrict__ boff,
                                                 int* __restrict__ rowptr,
                                                 int* __restrict__ colsrc) {
  __shared__ int cnt[NPB];
  __shared__ int loc[NPB + 1];
  __shared__ int2 buf[K4CAP];
  int b = blockIdx.x, t = threadIdx.x;
  int p0 = boff[b], p1 = boff[b + 1];
  int m = p1 - p0;
  int n0 = b * NPB;
  int nn = min(NPB, N_NODES - n0);
  for (int i = t; i < NPB; i += 256) cnt[i] = 0;
  __syncthreads();
  bool inlds = (m <= K4CAP);
  for (int i = t; i < m; i += 256) {
    int2 p = pairs[p0 + i];
    if (inlds) buf[i] = p;
    atomicAdd(&cnt[p.y - n0], 1);
  }
  __syncthreads();
  if (t == 0) {
    int run = 0;
#pragma unroll 1
    for (int j = 0; j < nn; ++j) { loc[j] = run; run += cnt[j]; }
    loc[nn] = run;
  }
  __syncthreads();
  for (int j = t; j < nn; j += 256) rowptr[n0 + j] = p0 + loc[j];
  if (t == 0 && n0 + nn == N_NODES) rowptr[N_NODES] = NET;
  for (int i = t; i < NPB; i += 256) cnt[i] = 0;
  __syncthreads();
  for (int i = t; i < m; i += 256) {
    int2 p = inlds ? buf[i] : pairs[p0 + i];
    int j = p.y - n0;
    int pos = atomicAdd(&cnt[j], 1);
    colsrc[p0 + loc[j] + pos] = p.x;
  }
}

// ---------------- setup: both weight transposes in one kernel ----------------

__global__ void transpose_both(const float* __restrict__ W1, ushort_t* __restrict__ W1t,
                               const float* __restrict__ W2, ushort_t* __restrict__ W2t) {
  int idx = blockIdx.x * blockDim.x + threadIdx.x;
  if (idx < F_IN * C1) {
    int k = idx / C1, n = idx - k * C1;
    W1t[(size_t)n * F_IN + k] = f2bf(W1[idx]);
  } else {
    int j = idx - F_IN * C1;
    if (j < C1 * F_OUT) {
      int k = j / F_OUT, n = j - k * F_OUT;
      W2t[(size_t)n * C1 + k] = f2bf(W2[j]);
    }
  }
}

// ---------------- MFMA bf16 GEMM with fused AL-logit epilogue ----------------
// CT=schar_t: int8 C + per-64ch scale (stride SCST/node). CT=ushort_t: bf16 C.

#define BKS 64
#define LDT 72

__device__ __forceinline__ us8 stage8(const ushort_t* p) { return *(const us8*)p; }
__device__ __forceinline__ us8 stage8(const float* p) {
  float4 f0 = *(const float4*)p;
  float4 f1 = *(const float4*)(p + 4);
  us8 o;
  o[0] = f2bf(f0.x); o[1] = f2bf(f0.y); o[2] = f2bf(f0.z); o[3] = f2bf(f0.w);
  o[4] = f2bf(f1.x); o[5] = f2bf(f1.y); o[6] = f2bf(f1.z); o[7] = f2bf(f1.w);
  return o;
}

template<int K, int NCOL, int AL_MODE, int SCST, typename AT, typename CT>
__global__ __launch_bounds__(256) void gemm_mfma(const AT* __restrict__ A,
                                                 const ushort_t* __restrict__ Bt,
                                                 CT* __restrict__ C,
                                                 float* __restrict__ scales,
                                                 const float* __restrict__ a_s,
                                                 const float* __restrict__ a_d,
                                                 float* __restrict__ als,
                                                 float* __restrict__ ald) {
  __shared__ __align__(16) char smem[2 * 128 * LDT * 2];
  ushort_t (*Asl)[LDT] = (ushort_t(*)[LDT])smem;
  ushort_t (*Bsl)[LDT] = (ushort_t(*)[LDT])(smem + 128 * LDT * 2);

  const int tid = threadIdx.x;
  const int lane = tid & 63;
  const int wave = tid >> 6;
  const int wr = wave >> 1, wc = wave & 1;
  const int row0 = blockIdx.y * 128;
  const int col0 = blockIdx.x * 128;
  const int l15 = lane & 15, l4 = lane >> 4;

  f32x4 acc[4][4] = {};

  for (int k0 = 0; k0 < K; k0 += BKS) {
#pragma unroll
    for (int i = 0; i < 4; ++i) {
      int seg = tid + i * 256;
      int row = seg >> 3, kq = (seg & 7) * 8;
      int arow = row0 + row;
      us8 v = {0, 0, 0, 0, 0, 0, 0, 0};
      if (arow < N_NODES) v = stage8(&A[(size_t)arow * K + k0 + kq]);
      *(us8*)&Asl[row][kq] = v;
    }
#pragma unroll
    for (int i = 0; i < 4; ++i) {
      int seg = tid + i * 256;
      int row = seg >> 3, kq = (seg & 7) * 8;
      us8 v = *(const us8*)&Bt[(size_t)(col0 + row) * K + k0 + kq];
      *(us8*)&Bsl[row][kq] = v;
    }
    __syncthreads();
#pragma unroll
    for (int kk = 0; kk < BKS; kk += 32) {
      bf16x8 af[4], bfr[4];
#pragma unroll
      for (int mi = 0; mi < 4; ++mi)
        af[mi] = *(const bf16x8*)&Asl[wr * 64 + mi * 16 + l15][kk + l4 * 8];
#pragma unroll
      for (int ni = 0; ni < 4; ++ni)
        bfr[ni] = *(const bf16x8*)&Bsl[wc * 64 + ni * 16 + l15][kk + l4 * 8];
#pragma unroll
      for (int mi = 0; mi < 4; ++mi)
#pragma unroll
        for (int ni = 0; ni < 4; ++ni)
          acc[mi][ni] = __builtin_amdgcn_mfma_f32_16x16x32_bf16(af[mi], bfr[ni], acc[mi][ni], 0, 0, 0);
    }
    __syncthreads();
  }

  // ---- fused attention-logit dots ----
  {
    const int albase = (AL_MODE == 1 ? col0 : 0) + wc * 64;
    float asv[4], adv[4];
#pragma unroll
    for (int ni = 0; ni < 4; ++ni) {
      asv[ni] = a_s[albase + ni * 16 + l15];
      adv[ni] = a_d[albase + ni * 16 + l15];
    }
#pragma unroll
    for (int mi = 0; mi < 4; ++mi) {
      float ps[4], pd[4];
#pragma unroll
      for (int r = 0; r < 4; ++r) {
        ps[r] = acc[mi][0][r] * asv[0] + acc[mi][1][r] * asv[1] +
                acc[mi][2][r] * asv[2] + acc[mi][3][r] * asv[3];
        pd[r] = acc[mi][0][r] * adv[0] + acc[mi][1][r] * adv[1] +
                acc[mi][2][r] * adv[2] + acc[mi][3][r] * adv[3];
      }
#pragma unroll
      for (int m = 1; m < 16; m <<= 1) {
#pragma unroll
        for (int r = 0; r < 4; ++r) {
          ps[r] += __shfl_xor(ps[r], m, 64);
          pd[r] += __shfl_xor(pd[r], m, 64);
        }
      }
      if (l15 == 0) {
#pragma unroll
        for (int r = 0; r < 4; ++r) {
          int row = row0 + wr * 64 + mi * 16 + l4 * 4 + r;
          if (row < N_NODES) {
            if (AL_MODE == 1) {
              int h = albase >> 6;
              als[row * 4 + h] = ps[r];
              ald[row * 4 + h] = pd[r];
            } else {
              atomicAdd(&als[row], ps[r]);
              atomicAdd(&ald[row], pd[r]);
            }
          }
        }
      }
    }
  }

  // ---- C epilogue: acc -> LDS bf16 bounce -> global (int8+scale or bf16) ----
  {
    ushort_t (*Ep)[136] = (ushort_t(*)[136])smem;
#pragma unroll
    for (int mi = 0; mi < 4; ++mi)
#pragma unroll
      for (int ni = 0; ni < 4; ++ni)
#pragma unroll
        for (int r = 0; r < 4; ++r)
          Ep[wr * 64 + mi * 16 + l4 * 4 + r][wc * 64 + ni * 16 + l15] = f2bf(acc[mi][ni][r]);
    __syncthreads();
    int row = tid >> 1, half = tid & 1;
    int grow = row0 + row;
    if (grow < N_NODES) {
      if constexpr (sizeof(CT) == 1) {
        float vals[64];
        float amax = 0.f;
#pragma unroll
        for (int i = 0; i < 8; ++i) {
          us8 v = *(const us8*)&Ep[row][half * 64 + i * 8];
#pragma unroll
          for (int j = 0; j < 8; ++j) {
            float f = b2f((ushort_t)v[j]);
            vals[i * 8 + j] = f;
            amax = fmaxf(amax, fabsf(f));
          }
        }
        float inv = amax > 0.f ? 127.f / amax : 0.f;
        scales[grow * SCST + (col0 >> 6) + half] = amax * (1.f / 127.f);
        schar_t ob[64];
#pragma unroll
        for (int i = 0; i < 64; ++i)
          ob[i] = (schar_t)(int)rintf(vals[i] * inv);
#pragma unroll
        for (int i = 0; i < 4; ++i)
          *(us8*)&C[(size_t)grow * NCOL + col0 + half * 64 + i * 16] =
              *(const us8*)&ob[i * 16];
      } else {
#pragma unroll
        for (int i = 0; i < 8; ++i)
          *(us8*)&C[(size_t)grow * NCOL + col0 + half * 64 + i * 8] =
              *(const us8*)&Ep[row][half * 64 + i * 8];
      }
    }
  }
}

// ---------------- fused softmax + gather aggregation (all int8) ----------------

// layer1 (round-15 config, 28 VGPR): half-wave (32 lanes x 8B) per edge;
// 2 edges/wave concurrent, unroll 4 -> 8 gathers in flight.
__global__ __launch_bounds__(256) void agg1(const int* __restrict__ rowptr,
                                            const int* __restrict__ colsrc,
                                            const schar_t* __restrict__ Hq,
                                            const float* __restrict__ Sc,
                                            const float* __restrict__ als,
                                            const float* __restrict__ ald,
                                            const float* __restrict__ b1,
                                            ushort_t* __restrict__ X2b) {
  int wave = threadIdx.x >> 6, lane = threadIdx.x & 63;
  int n = blockIdx.x * 4 + wave;
  if (n >= N_NODES) return;
  int half = lane >> 5, li = lane & 31, h = li >> 3;
  float ad = ald[n * 4 + h];
  int beg = rowptr[n], end = rowptr[n + 1];
  float a[8] = {};
  float s = 0.f;
  int i = beg + half;
  for (; i + 6 < end; i += 8) {
    int s0 = colsrc[i], s1 = colsrc[i + 2], s2 = colsrc[i + 4], s3 = colsrc[i + 6];
    float sc0 = als[s0 * 4 + h] + ad;
    float sc1 = als[s1 * 4 + h] + ad;
    float sc2 = als[s2 * 4 + h] + ad;
    float sc3 = als[s3 * 4 + h] + ad;
    float q0 = Sc[s0 * 4 + h], q1 = Sc[s1 * 4 + h], q2 = Sc[s2 * 4 + h], q3 = Sc[s3 * 4 + h];
    uint2 v0 = *(const uint2*)&Hq[(size_t)s0 * C1 + li * 8];
    uint2 v1 = *(const uint2*)&Hq[(size_t)s1 * C1 + li * 8];
    uint2 v2 = *(const uint2*)&Hq[(size_t)s2 * C1 + li * 8];
    uint2 v3 = *(const uint2*)&Hq[(size_t)s3 * C1 + li * 8];
    sc0 = sc0 > 0.f ? sc0 : NEG_SLOPE * sc0;
    sc1 = sc1 > 0.f ? sc1 : NEG_SLOPE * sc1;
    sc2 = sc2 > 0.f ? sc2 : NEG_SLOPE * sc2;
    sc3 = sc3 > 0.f ? sc3 : NEG_SLOPE * sc3;
    float w0 = __expf(sc0), w1 = __expf(sc1), w2 = __expf(sc2), w3 = __expf(sc3);
    s += (w0 + w1) + (w2 + w3);
    fma8q(w0 * q0, v0, a); fma8q(w1 * q1, v1, a);
    fma8q(w2 * q2, v2, a); fma8q(w3 * q3, v3, a);
  }
  for (; i + 2 < end; i += 4) {
    int s0 = colsrc[i], s1 = colsrc[i + 2];
    float sc0 = als[s0 * 4 + h] + ad;
    float sc1 = als[s1 * 4 + h] + ad;
    float q0 = Sc[s0 * 4 + h], q1 = Sc[s1 * 4 + h];
    uint2 v0 = *(const uint2*)&Hq[(size_t)s0 * C1 + li * 8];
    uint2 v1 = *(const uint2*)&Hq[(size_t)s1 * C1 + li * 8];
    sc0 = sc0 > 0.f ? sc0 : NEG_SLOPE * sc0;
    sc1 = sc1 > 0.f ? sc1 : NEG_SLOPE * sc1;
    float w0 = __expf(sc0), w1 = __expf(sc1);
    s += w0 + w1;
    fma8q(w0 * q0, v0, a); fma8q(w1 * q1, v1, a);
  }
  for (; i < end; i += 2) {
    int s0 = colsrc[i];
    float sc0 = als[s0 * 4 + h] + ad;
    float q0 = Sc[s0 * 4 + h];
    uint2 v0 = *(const uint2*)&Hq[(size_t)s0 * C1 + li * 8];
    sc0 = sc0 > 0.f ? sc0 : NEG_SLOPE * sc0;
    float w0 = __expf(sc0);
    s += w0;
    fma8q(w0 * q0, v0, a);
  }
#pragma unroll
  for (int j = 0; j < 8; ++j) a[j] += __shfl_xor(a[j], 32, 64);
  s += __shfl_xor(s, 32, 64);
  if (lane < 32) {
    float si = 1.f / s;
    int c = li * 8;
    ushort_t o[8];
#pragma unroll
    for (int j = 0; j < 8; ++j)
      o[j] = f2bf(fmaxf(a[j] * si + b1[c + j], 0.f));
    *(us8*)&X2b[(size_t)n * C1 + c] = *(const us8*)o;
  }
}

// layer2 int8: quarter-wave (16 lanes x 8B = 128 ch) per edge; 4 edges/wave,
// unroll 2 -> 8 in flight; a[8] keeps VGPR ~28.
__global__ __launch_bounds__(256) void agg2(const int* __restrict__ rowptr,
                                            const int* __restrict__ colsrc,
                                            const schar_t* __restrict__ Hq,
                                            const float* __restrict__ Sc,
                                            const float* __restrict__ als,
                                            const float* __restrict__ ald,
                                            const float* __restrict__ b2,
                                            float* __restrict__ out) {
  int wave = threadIdx.x >> 6, lane = threadIdx.x & 63;
  int n = blockIdx.x * 4 + wave;
  if (n >= N_NODES) return;
  int quarter = lane >> 4, li = lane & 15;
  int hb = li >> 3;                     // 8 ch/lane: c = li*8, 64-block = c/64
  float ad = ald[n];
  int beg = rowptr[n], end = rowptr[n + 1];
  float a[8] = {};
  float s = 0.f;
  int i = beg + quarter;
  for (; i + 4 < end; i += 8) {
    int s0 = colsrc[i], s1 = colsrc[i + 4];
    float sc0 = als[s0] + ad;
    float sc1 = als[s1] + ad;
    float q0 = Sc[s0 * 2 + hb], q1 = Sc[s1 * 2 + hb];
    uint2 v0 = *(const uint2*)&Hq[(size_t)s0 * F_OUT + li * 8];
    uint2 v1 = *(const uint2*)&Hq[(size_t)s1 * F_OUT + li * 8];
    sc0 = sc0 > 0.f ? sc0 : NEG_SLOPE * sc0;
    sc1 = sc1 > 0.f ? sc1 : NEG_SLOPE * sc1;
    float w0 = __expf(sc0), w1 = __expf(sc1);
    s += w0 + w1;
    fma8q(w0 * q0, v0, a); fma8q(w1 * q1, v1, a);
  }
  for (; i < end; i += 4) {
    int s0 = colsrc[i];
    float sc0 = als[s0] + ad;
    float q0 = Sc[s0 * 2 + hb];
    uint2 v0 = *(const uint2*)&Hq[(size_t)s0 * F_OUT + li * 8];
    sc0 = sc0 > 0.f ? sc0 : NEG_SLOPE * sc0;
    float w0 = __expf(sc0);
    s += w0;
    fma8q(w0 * q0, v0, a);
  }
#pragma unroll
  for (int j = 0; j < 8; ++j) a[j] += __shfl_xor(a[j], 16, 64);
#pragma unroll
  for (int j = 0; j < 8; ++j) a[j] += __shfl_xor(a[j], 32, 64);
  s += __shfl_xor(s, 16, 64);
  s += __shfl_xor(s, 32, 64);
  if (lane < 16) {
    float si = 1.f / s;
    int c = li * 8;
    float4 o0, o1;
    o0.x = a[0] * si + b2[c + 0]; o0.y = a[1] * si + b2[c + 1];
    o0.z = a[2] * si + b2[c + 2]; o0.w = a[3] * si + b2[c + 3];
    o1.x = a[4] * si + b2[c + 4]; o1.y = a[5] * si + b2[c + 5];
    o1.z = a[6] * si + b2[c + 6]; o1.w = a[7] * si + b2[c + 7];
    *(float4*)&out[(size_t)n * F_OUT + c] = o0;
    *(float4*)&out[(size_t)n * F_OUT + c + 4] = o1;
  }
}

// ---------------- launch ----------------

extern "C" void kernel_launch(void* const* d_in, const int* in_sizes, int n_in,
                              void* d_out, int out_size, void* d_ws, size_t ws_size,
                              hipStream_t stream) {
  const float* X   = (const float*)d_in[0];
  const int*   EI  = (const int*)d_in[1];
  const float* W1  = (const float*)d_in[2];
  const float* a1s = (const float*)d_in[3];
  const float* a1d = (const float*)d_in[4];
  const float* b1  = (const float*)d_in[5];
  const float* W2  = (const float*)d_in[6];
  const float* a2s = (const float*)d_in[7];
  const float* a2d = (const float*)d_in[8];
  const float* b2  = (const float*)d_in[9];
  float* out = (float*)d_out;

  char* ws = (char*)d_ws;
  size_t off = 0;
  auto alloc = [&](size_t bytes) -> void* {
    void* p = ws + off;
    off += (bytes + 255) & ~(size_t)255;
    return p;
  };
  // zero-init block first (single memset)
  int* bcnt       = (int*)alloc((size_t)NBUCK * BPAD * 4);
  int* bfill      = (int*)alloc((size_t)NBUCK * BPAD * 4);
  float* ALS2     = (float*)alloc((size_t)N_NODES * 4);
  float* ALD2     = (float*)alloc((size_t)N_NODES * 4);
  size_t zero_span = off;
  int* boff       = (int*)alloc((size_t)(NBUCK + 1) * 4);
  int* rowptr     = (int*)alloc((size_t)(N_NODES + 1) * 4);
  int* colsrc     = (int*)alloc((size_t)NET * 4);
  int2* pairs     = (int2*)alloc((size_t)NET * 8);
  ushort_t* W1t   = (ushort_t*)alloc((size_t)C1 * F_IN * 2);
  ushort_t* W2t   = (ushort_t*)alloc((size_t)F_OUT * C1 * 2);
  schar_t* H1q    = (schar_t*)alloc((size_t)N_NODES * C1);        // 12.8MB int8
  float* SC1      = (float*)alloc((size_t)N_NODES * HEADS * 4);
  float* SC2      = (float*)alloc((size_t)N_NODES * 2 * 4);
  float* ALS1     = (float*)alloc((size_t)N_NODES * HEADS * 4);
  float* ALD1     = (float*)alloc((size_t)N_NODES * HEADS * 4);
  ushort_t* X2b   = (ushort_t*)alloc((size_t)N_NODES * C1 * 2);
  schar_t* H2q = H1q;  // H1 dead after agg1; layer-2 int8 table 6.4MB <= 12.8MB

  hipMemsetAsync(ws, 0, zero_span, stream);

  // bucketed CSR build (block-owned scatter runs)
  bucket_count<<<128, 256, 0, stream>>>(EI, bcnt);
  scan_buckets<<<1, 1024, 0, stream>>>(bcnt, boff);
  bucket_scatter_blocked<<<(NET + SCHUNK - 1) / SCHUNK, 1024, 0, stream>>>(EI, boff, bfill, pairs);
  build_csr<<<NBUCK, 256, 0, stream>>>(pairs, boff, rowptr, colsrc);

  // weight transposes (bf16), single launch
  transpose_both<<<(F_IN * C1 + C1 * F_OUT + 255) / 256, 256, 0, stream>>>(W1, W1t, W2, W2t);

  // layer 1 (A = fp32 X converted in staging; C = int8 + 4 scales/node)
  {
    dim3 grid(C1 / 128, (N_NODES + 127) / 128);
    gemm_mfma<F_IN, C1, 1, 4, float, schar_t><<<grid, 256, 0, stream>>>(
        X, W1t, H1q, SC1, a1s, a1d, ALS1, ALD1);
  }
  agg1<<<(N_NODES + 3) / 4, 256, 0, stream>>>(rowptr, colsrc, H1q, SC1, ALS1, ALD1, b1, X2b);

  // layer 2 (A = bf16 X2; C = int8 + 2 scales/node)
  {
    dim3 grid(F_OUT / 128, (N_NODES + 127) / 128);
    gemm_mfma<C1, F_OUT, 2, 2, ushort_t, schar_t><<<grid, 256, 0, stream>>>(
        X2b, W2t, H2q, SC2, a2s, a2d, ALS2, ALD2);
  }
  agg2<<<(N_NODES + 3) / 4, 256, 0, stream>>>(rowptr, colsrc, H2q, SC2, ALS2, ALD2, b2, out);
}

// Round 18
// 168.841 us; speedup vs baseline: 1.1543x; 1.0115x over previous
//
#include <hip/hip_runtime.h>
#include <math.h>

#define N_NODES 50000
#define F_IN    128
#define HIDC    64
#define HEADS   4
#define C1      (HEADS*HIDC)   // 256
#define F_OUT   128
#define NE      800000
#define NET     (NE + N_NODES) // 850000 edges incl self-loops
#define NEG_SLOPE 0.2f

#define NPB   49               // nodes per bucket
#define NBUCK 1021             // ceil(N_NODES / NPB)
#define BPAD  16               // counter padding (ints): 1 counter per 64B line
#define K4CAP 2048             // build_csr LDS staging cap (mean 833)
#define SCHUNK 8192            // edges per scatter chunk
#define GEMM1_BX (C1 / 128)                     // 2
#define GEMM1_BY ((N_NODES + 127) / 128)        // 391
#define GEMM1_BLOCKS (GEMM1_BX * GEMM1_BY)      // 782
#define SCAT_BLOCKS ((NET + SCHUNK - 1) / SCHUNK) // 104
#define CNT_BLOCKS 128
#define TRN_ELEMS (F_IN * C1 + C1 * F_OUT)      // 65536
#define TRN_BLOCKS (TRN_ELEMS / 256)            // 256

typedef unsigned short ushort_t;
typedef signed char    schar_t;
typedef __attribute__((ext_vector_type(8))) short bf16x8;
typedef __attribute__((ext_vector_type(8))) unsigned short us8;
typedef __attribute__((ext_vector_type(4))) float f32x4;

#define SMEMSZ (2 * 128 * 72 * 2)   // 36864B, gemm staging / epilogue / scatter tables

__device__ __forceinline__ float b2f(ushort_t x) {
  return __uint_as_float(((unsigned int)x) << 16);
}
__device__ __forceinline__ ushort_t f2bf(float f) {  // RNE, no NaN expected
  unsigned int u = __float_as_uint(f);
  return (ushort_t)((u + 0x7fffu + ((u >> 16) & 1u)) >> 16);
}

// int8 x8 decode: wsc = w * scale folded; denominator uses raw w.
__device__ __forceinline__ void fma8q(float wsc, uint2 vv, float* a) {
  int x = (int)vv.x, y = (int)vv.y;
  a[0] = fmaf(wsc, (float)(schar_t)(x),        a[0]);
  a[1] = fmaf(wsc, (float)(schar_t)(x >> 8),   a[1]);
  a[2] = fmaf(wsc, (float)(schar_t)(x >> 16),  a[2]);
  a[3] = fmaf(wsc, (float)(x >> 24),           a[3]);
  a[4] = fmaf(wsc, (float)(schar_t)(y),        a[4]);
  a[5] = fmaf(wsc, (float)(schar_t)(y >> 8),   a[5]);
  a[6] = fmaf(wsc, (float)(schar_t)(y >> 16),  a[6]);
  a[7] = fmaf(wsc, (float)(y >> 24),           a[7]);
}

// ---------------- K1: fused bucket_count + weight transposes ----------------

__global__ __launch_bounds__(256) void setup_fused(const int* __restrict__ ei,
                                                   int* __restrict__ bcnt,
                                                   const float* __restrict__ W1,
                                                   ushort_t* __restrict__ W1t,
                                                   const float* __restrict__ W2,
                                                   ushort_t* __restrict__ W2t) {
  __shared__ int hist[NBUCK];
  int bid = blockIdx.x;
  if (bid < CNT_BLOCKS) {
    for (int i = threadIdx.x; i < NBUCK; i += 256) hist[i] = 0;
    __syncthreads();
    int stride = CNT_BLOCKS * 256;
    for (int e = bid * 256 + threadIdx.x; e < NET; e += stride) {
      int d = (e < NE) ? ei[NE + e] : (e - NE);
      atomicAdd(&hist[d / NPB], 1);
    }
    __syncthreads();
    for (int i = threadIdx.x; i < NBUCK; i += 256)
      if (hist[i]) atomicAdd(&bcnt[i * BPAD], hist[i]);
  } else {
    int idx = (bid - CNT_BLOCKS) * 256 + threadIdx.x;
    if (idx < F_IN * C1) {
      int k = idx / C1, n = idx - k * C1;
      W1t[(size_t)n * F_IN + k] = f2bf(W1[idx]);
    } else if (idx < TRN_ELEMS) {
      int j = idx - F_IN * C1;
      int k = j / F_OUT, n = j - k * F_OUT;
      W2t[(size_t)n * C1 + k] = f2bf(W2[j]);
    }
  }
}

__global__ __launch_bounds__(1024) void scan_buckets(const int* __restrict__ bcnt,
                                                     int* __restrict__ boff) {
  __shared__ int sh[1024];
  int t = threadIdx.x;
  sh[t] = (t < NBUCK) ? bcnt[t * BPAD] : 0;
  __syncthreads();
#pragma unroll
  for (int off = 1; off < 1024; off <<= 1) {
    int u = (t >= off) ? sh[t - off] : 0;
    __syncthreads();
    sh[t] += u;
    __syncthreads();
  }
  if (t < NBUCK) boff[t + 1] = sh[t];
  if (t == 0) boff[0] = 0;
}

// ---------------- gemm body (shared by standalone + fused kernels) ----------------
// CT=schar_t: int8 C + per-64ch scale (stride SCST/node). CT=ushort_t: bf16 C.

#define BKS 64
#define LDT 72

__device__ __forceinline__ us8 stage8(const ushort_t* p) { return *(const us8*)p; }
__device__ __forceinline__ us8 stage8(const float* p) {
  float4 f0 = *(const float4*)p;
  float4 f1 = *(const float4*)(p + 4);
  us8 o;
  o[0] = f2bf(f0.x); o[1] = f2bf(f0.y); o[2] = f2bf(f0.z); o[3] = f2bf(f0.w);
  o[4] = f2bf(f1.x); o[5] = f2bf(f1.y); o[6] = f2bf(f1.z); o[7] = f2bf(f1.w);
  return o;
}

template<int K, int NCOL, int AL_MODE, int SCST, typename AT, typename CT>
__device__ void gemm_body(char* smem, int bx, int by,
                          const AT* __restrict__ A, const ushort_t* __restrict__ Bt,
                          CT* __restrict__ C, float* __restrict__ scales,
                          const float* __restrict__ a_s, const float* __restrict__ a_d,
                          float* __restrict__ als, float* __restrict__ ald) {
  ushort_t (*Asl)[LDT] = (ushort_t(*)[LDT])smem;
  ushort_t (*Bsl)[LDT] = (ushort_t(*)[LDT])(smem + 128 * LDT * 2);

  const int tid = threadIdx.x;
  const int lane = tid & 63;
  const int wave = tid >> 6;
  const int wr = wave >> 1, wc = wave & 1;
  const int row0 = by * 128;
  const int col0 = bx * 128;
  const int l15 = lane & 15, l4 = lane >> 4;

  f32x4 acc[4][4] = {};

  for (int k0 = 0; k0 < K; k0 += BKS) {
#pragma unroll
    for (int i = 0; i < 4; ++i) {
      int seg = tid + i * 256;
      int row = seg >> 3, kq = (seg & 7) * 8;
      int arow = row0 + row;
      us8 v = {0, 0, 0, 0, 0, 0, 0, 0};
      if (arow < N_NODES) v = stage8(&A[(size_t)arow * K + k0 + kq]);
      *(us8*)&Asl[row][kq] = v;
    }
#pragma unroll
    for (int i = 0; i < 4; ++i) {
      int seg = tid + i * 256;
      int row = seg >> 3, kq = (seg & 7) * 8;
      us8 v = *(const us8*)&Bt[(size_t)(col0 + row) * K + k0 + kq];
      *(us8*)&Bsl[row][kq] = v;
    }
    __syncthreads();
#pragma unroll
    for (int kk = 0; kk < BKS; kk += 32) {
      bf16x8 af[4], bfr[4];
#pragma unroll
      for (int mi = 0; mi < 4; ++mi)
        af[mi] = *(const bf16x8*)&Asl[wr * 64 + mi * 16 + l15][kk + l4 * 8];
#pragma unroll
      for (int ni = 0; ni < 4; ++ni)
        bfr[ni] = *(const bf16x8*)&Bsl[wc * 64 + ni * 16 + l15][kk + l4 * 8];
#pragma unroll
      for (int mi = 0; mi < 4; ++mi)
#pragma unroll
        for (int ni = 0; ni < 4; ++ni)
          acc[mi][ni] = __builtin_amdgcn_mfma_f32_16x16x32_bf16(af[mi], bfr[ni], acc[mi][ni], 0, 0, 0);
    }
    __syncthreads();
  }

  // ---- fused attention-logit dots ----
  {
    const int albase = (AL_MODE == 1 ? col0 : 0) + wc * 64;
    float asv[4], adv[4];
#pragma unroll
    for (int ni = 0; ni < 4; ++ni) {
      asv[ni] = a_s[albase + ni * 16 + l15];
      adv[ni] = a_d[albase + ni * 16 + l15];
    }
#pragma unroll
    for (int mi = 0; mi < 4; ++mi) {
      float ps[4], pd[4];
#pragma unroll
      for (int r = 0; r < 4; ++r) {
        ps[r] = acc[mi][0][r] * asv[0] + acc[mi][1][r] * asv[1] +
                acc[mi][2][r] * asv[2] + acc[mi][3][r] * asv[3];
        pd[r] = acc[mi][0][r] * adv[0] + acc[mi][1][r] * adv[1] +
                acc[mi][2][r] * adv[2] + acc[mi][3][r] * adv[3];
      }
#pragma unroll
      for (int m = 1; m < 16; m <<= 1) {
#pragma unroll
        for (int r = 0; r < 4; ++r) {
          ps[r] += __shfl_xor(ps[r], m, 64);
          pd[r] += __shfl_xor(pd[r], m, 64);
        }
      }
      if (l15 == 0) {
#pragma unroll
        for (int r = 0; r < 4; ++r) {
          int row = row0 + wr * 64 + mi * 16 + l4 * 4 + r;
          if (row < N_NODES) {
            if (AL_MODE == 1) {
              int h = albase >> 6;
              als[row * 4 + h] = ps[r];
              ald[row * 4 + h] = pd[r];
            } else {
              atomicAdd(&als[row], ps[r]);
              atomicAdd(&ald[row], pd[r]);
            }
          }
        }
      }
    }
  }

  // ---- C epilogue: acc -> LDS bf16 bounce -> global (int8+scale or bf16) ----
  {
    ushort_t (*Ep)[136] = (ushort_t(*)[136])smem;
#pragma unroll
    for (int mi = 0; mi < 4; ++mi)
#pragma unroll
      for (int ni = 0; ni < 4; ++ni)
#pragma unroll
        for (int r = 0; r < 4; ++r)
          Ep[wr * 64 + mi * 16 + l4 * 4 + r][wc * 64 + ni * 16 + l15] = f2bf(acc[mi][ni][r]);
    __syncthreads();
    int row = tid >> 1, half = tid & 1;
    int grow = row0 + row;
    if (grow < N_NODES) {
      if constexpr (sizeof(CT) == 1) {
        float vals[64];
        float amax = 0.f;
#pragma unroll
        for (int i = 0; i < 8; ++i) {
          us8 v = *(const us8*)&Ep[row][half * 64 + i * 8];
#pragma unroll
          for (int j = 0; j < 8; ++j) {
            float f = b2f((ushort_t)v[j]);
            vals[i * 8 + j] = f;
            amax = fmaxf(amax, fabsf(f));
          }
        }
        float inv = amax > 0.f ? 127.f / amax : 0.f;
        scales[grow * SCST + (col0 >> 6) + half] = amax * (1.f / 127.f);
        schar_t ob[64];
#pragma unroll
        for (int i = 0; i < 64; ++i)
          ob[i] = (schar_t)(int)rintf(vals[i] * inv);
#pragma unroll
        for (int i = 0; i < 4; ++i)
          *(us8*)&C[(size_t)grow * NCOL + col0 + half * 64 + i * 16] =
              *(const us8*)&ob[i * 16];
      } else {
#pragma unroll
        for (int i = 0; i < 8; ++i)
          *(us8*)&C[(size_t)grow * NCOL + col0 + half * 64 + i * 8] =
              *(const us8*)&Ep[row][half * 64 + i * 8];
      }
    }
  }
}

template<int K, int NCOL, int AL_MODE, int SCST, typename AT, typename CT>
__global__ __launch_bounds__(256) void gemm_mfma(const AT* __restrict__ A,
                                                 const ushort_t* __restrict__ Bt,
                                                 CT* __restrict__ C,
                                                 float* __restrict__ scales,
                                                 const float* __restrict__ a_s,
                                                 const float* __restrict__ a_d,
                                                 float* __restrict__ als,
                                                 float* __restrict__ ald) {
  __shared__ __align__(16) char smem[SMEMSZ];
  gemm_body<K, NCOL, AL_MODE, SCST, AT, CT>(smem, blockIdx.x, blockIdx.y,
                                            A, Bt, C, scales, a_s, a_d, als, ald);
}

// ---------------- K3: fused gemm1 + block-owned bucket scatter ----------------
// gemm blocks [0, GEMM1_BLOCKS); scatter blocks [GEMM1_BLOCKS, +SCAT_BLOCKS).
// Independent work; memory-bound scatter overlaps under MFMA-bound gemm.

__global__ __launch_bounds__(256) void gemm1_plus_scatter(
    const float* __restrict__ X, const ushort_t* __restrict__ W1t,
    schar_t* __restrict__ H1q, float* __restrict__ SC1,
    const float* __restrict__ a1s, const float* __restrict__ a1d,
    float* __restrict__ ALS1, float* __restrict__ ALD1,
    const int* __restrict__ ei, const int* __restrict__ boff,
    int* __restrict__ bfill, int2* __restrict__ pairs) {
  __shared__ __align__(16) char smem[SMEMSZ];
  int bid = blockIdx.x;
  if (bid < GEMM1_BLOCKS) {
    gemm_body<F_IN, C1, 1, 4, float, schar_t>(smem, bid % GEMM1_BX, bid / GEMM1_BX,
                                              X, W1t, H1q, SC1, a1s, a1d, ALS1, ALD1);
  } else {
    int* hist  = (int*)smem;
    int* gbase = hist + NBUCK;
    int* fill  = gbase + NBUCK;
    int chunk = bid - GEMM1_BLOCKS;
    int c0 = chunk * SCHUNK;
    int cend = min(c0 + SCHUNK, NET);
    for (int i = threadIdx.x; i < NBUCK; i += 256) { hist[i] = 0; fill[i] = 0; }
    __syncthreads();
    for (int e = c0 + threadIdx.x; e < cend; e += 256) {
      int d = (e < NE) ? ei[NE + e] : (e - NE);
      atomicAdd(&hist[d / NPB], 1);
    }
    __syncthreads();
    for (int i = threadIdx.x; i < NBUCK; i += 256)
      if (hist[i]) gbase[i] = boff[i] + atomicAdd(&bfill[i * BPAD], hist[i]);
    __syncthreads();
    for (int e = c0 + threadIdx.x; e < cend; e += 256) {
      int s, d;
      if (e < NE) { s = ei[e]; d = ei[NE + e]; }
      else        { s = e - NE; d = s; }
      int b = d / NPB;
      int lpos = atomicAdd(&fill[b], 1);
      pairs[gbase[b] + lpos] = make_int2(s, d);
    }
  }
}

// one block per bucket: local CSR + locality-friendly colsrc writes.
__global__ __launch_bounds__(256) void build_csr(const int2* __restrict__ pairs,
                                                 const int* __restrict__ boff,
                                                 int* __restrict__ rowptr,
                                                 int* __restrict__ colsrc) {
  __shared__ int cnt[NPB];
  __shared__ int loc[NPB + 1];
  __shared__ int2 buf[K4CAP];
  int b = blockIdx.x, t = threadIdx.x;
  int p0 = boff[b], p1 = boff[b + 1];
  int m = p1 - p0;
  int n0 = b * NPB;
  int nn = min(NPB, N_NODES - n0);
  for (int i = t; i < NPB; i += 256) cnt[i] = 0;
  __syncthreads();
  bool inlds = (m <= K4CAP);
  for (int i = t; i < m; i += 256) {
    int2 p = pairs[p0 + i];
    if (inlds) buf[i] = p;
    atomicAdd(&cnt[p.y - n0], 1);
  }
  __syncthreads();
  if (t == 0) {
    int run = 0;
#pragma unroll 1
    for (int j = 0; j < nn; ++j) { loc[j] = run; run += cnt[j]; }
    loc[nn] = run;
  }
  __syncthreads();
  for (int j = t; j < nn; j += 256) rowptr[n0 + j] = p0 + loc[j];
  if (t == 0 && n0 + nn == N_NODES) rowptr[N_NODES] = NET;
  for (int i = t; i < NPB; i += 256) cnt[i] = 0;
  __syncthreads();
  for (int i = t; i < m; i += 256) {
    int2 p = inlds ? buf[i] : pairs[p0 + i];
    int j = p.y - n0;
    int pos = atomicAdd(&cnt[j], 1);
    colsrc[p0 + loc[j] + pos] = p.x;
  }
}

// ---------------- fused softmax + gather aggregation (all int8) ----------------

// layer1: half-wave (32 lanes x 8B) per edge; 2 edges/wave, unroll 4 -> 8 in flight.
__global__ __launch_bounds__(256) void agg1(const int* __restrict__ rowptr,
                                            const int* __restrict__ colsrc,
                                            const schar_t* __restrict__ Hq,
                                            const float* __restrict__ Sc,
                                            const float* __restrict__ als,
                                            const float* __restrict__ ald,
                                            const float* __restrict__ b1,
                                            ushort_t* __restrict__ X2b) {
  int wave = threadIdx.x >> 6, lane = threadIdx.x & 63;
  int n = blockIdx.x * 4 + wave;
  if (n >= N_NODES) return;
  int half = lane >> 5, li = lane & 31, h = li >> 3;
  float ad = ald[n * 4 + h];
  int beg = rowptr[n], end = rowptr[n + 1];
  float a[8] = {};
  float s = 0.f;
  int i = beg + half;
  for (; i + 6 < end; i += 8) {
    int s0 = colsrc[i], s1 = colsrc[i + 2], s2 = colsrc[i + 4], s3 = colsrc[i + 6];
    float sc0 = als[s0 * 4 + h] + ad;
    float sc1 = als[s1 * 4 + h] + ad;
    float sc2 = als[s2 * 4 + h] + ad;
    float sc3 = als[s3 * 4 + h] + ad;
    float q0 = Sc[s0 * 4 + h], q1 = Sc[s1 * 4 + h], q2 = Sc[s2 * 4 + h], q3 = Sc[s3 * 4 + h];
    uint2 v0 = *(const uint2*)&Hq[(size_t)s0 * C1 + li * 8];
    uint2 v1 = *(const uint2*)&Hq[(size_t)s1 * C1 + li * 8];
    uint2 v2 = *(const uint2*)&Hq[(size_t)s2 * C1 + li * 8];
    uint2 v3 = *(const uint2*)&Hq[(size_t)s3 * C1 + li * 8];
    sc0 = sc0 > 0.f ? sc0 : NEG_SLOPE * sc0;
    sc1 = sc1 > 0.f ? sc1 : NEG_SLOPE * sc1;
    sc2 = sc2 > 0.f ? sc2 : NEG_SLOPE * sc2;
    sc3 = sc3 > 0.f ? sc3 : NEG_SLOPE * sc3;
    float w0 = __expf(sc0), w1 = __expf(sc1), w2 = __expf(sc2), w3 = __expf(sc3);
    s += (w0 + w1) + (w2 + w3);
    fma8q(w0 * q0, v0, a); fma8q(w1 * q1, v1, a);
    fma8q(w2 * q2, v2, a); fma8q(w3 * q3, v3, a);
  }
  for (; i + 2 < end; i += 4) {
    int s0 = colsrc[i], s1 = colsrc[i + 2];
    float sc0 = als[s0 * 4 + h] + ad;
    float sc1 = als[s1 * 4 + h] + ad;
    float q0 = Sc[s0 * 4 + h], q1 = Sc[s1 * 4 + h];
    uint2 v0 = *(const uint2*)&Hq[(size_t)s0 * C1 + li * 8];
    uint2 v1 = *(const uint2*)&Hq[(size_t)s1 * C1 + li * 8];
    sc0 = sc0 > 0.f ? sc0 : NEG_SLOPE * sc0;
    sc1 = sc1 > 0.f ? sc1 : NEG_SLOPE * sc1;
    float w0 = __expf(sc0), w1 = __expf(sc1);
    s += w0 + w1;
    fma8q(w0 * q0, v0, a); fma8q(w1 * q1, v1, a);
  }
  for (; i < end; i += 2) {
    int s0 = colsrc[i];
    float sc0 = als[s0 * 4 + h] + ad;
    float q0 = Sc[s0 * 4 + h];
    uint2 v0 = *(const uint2*)&Hq[(size_t)s0 * C1 + li * 8];
    sc0 = sc0 > 0.f ? sc0 : NEG_SLOPE * sc0;
    float w0 = __expf(sc0);
    s += w0;
    fma8q(w0 * q0, v0, a);
  }
#pragma unroll
  for (int j = 0; j < 8; ++j) a[j] += __shfl_xor(a[j], 32, 64);
  s += __shfl_xor(s, 32, 64);
  if (lane < 32) {
    float si = 1.f / s;
    int c = li * 8;
    ushort_t o[8];
#pragma unroll
    for (int j = 0; j < 8; ++j)
      o[j] = f2bf(fmaxf(a[j] * si + b1[c + j], 0.f));
    *(us8*)&X2b[(size_t)n * C1 + c] = *(const us8*)o;
  }
}

// layer2 int8: quarter-wave (16 lanes x 8B = 128 ch) per edge; 4 edges/wave,
// unroll 2 -> 8 in flight.
__global__ __launch_bounds__(256) void agg2(const int* __restrict__ rowptr,
                                            const int* __restrict__ colsrc,
                                            const schar_t* __restrict__ Hq,
                                            const float* __restrict__ Sc,
                                            const float* __restrict__ als,
                                            const float* __restrict__ ald,
                                            const float* __restrict__ b2,
                                            float* __restrict__ out) {
  int wave = threadIdx.x >> 6, lane = threadIdx.x & 63;
  int n = blockIdx.x * 4 + wave;
  if (n >= N_NODES) return;
  int quarter = lane >> 4, li = lane & 15;
  int hb = li >> 3;
  float ad = ald[n];
  int beg = rowptr[n], end = rowptr[n + 1];
  float a[8] = {};
  float s = 0.f;
  int i = beg + quarter;
  for (; i + 4 < end; i += 8) {
    int s0 = colsrc[i], s1 = colsrc[i + 4];
    float sc0 = als[s0] + ad;
    float sc1 = als[s1] + ad;
    float q0 = Sc[s0 * 2 + hb], q1 = Sc[s1 * 2 + hb];
    uint2 v0 = *(const uint2*)&Hq[(size_t)s0 * F_OUT + li * 8];
    uint2 v1 = *(const uint2*)&Hq[(size_t)s1 * F_OUT + li * 8];
    sc0 = sc0 > 0.f ? sc0 : NEG_SLOPE * sc0;
    sc1 = sc1 > 0.f ? sc1 : NEG_SLOPE * sc1;
    float w0 = __expf(sc0), w1 = __expf(sc1);
    s += w0 + w1;
    fma8q(w0 * q0, v0, a); fma8q(w1 * q1, v1, a);
  }
  for (; i < end; i += 4) {
    int s0 = colsrc[i];
    float sc0 = als[s0] + ad;
    float q0 = Sc[s0 * 2 + hb];
    uint2 v0 = *(const uint2*)&Hq[(size_t)s0 * F_OUT + li * 8];
    sc0 = sc0 > 0.f ? sc0 : NEG_SLOPE * sc0;
    float w0 = __expf(sc0);
    s += w0;
    fma8q(w0 * q0, v0, a);
  }
#pragma unroll
  for (int j = 0; j < 8; ++j) a[j] += __shfl_xor(a[j], 16, 64);
#pragma unroll
  for (int j = 0; j < 8; ++j) a[j] += __shfl_xor(a[j], 32, 64);
  s += __shfl_xor(s, 16, 64);
  s += __shfl_xor(s, 32, 64);
  if (lane < 16) {
    float si = 1.f / s;
    int c = li * 8;
    float4 o0, o1;
    o0.x = a[0] * si + b2[c + 0]; o0.y = a[1] * si + b2[c + 1];
    o0.z = a[2] * si + b2[c + 2]; o0.w = a[3] * si + b2[c + 3];
    o1.x = a[4] * si + b2[c + 4]; o1.y = a[5] * si + b2[c + 5];
    o1.z = a[6] * si + b2[c + 6]; o1.w = a[7] * si + b2[c + 7];
    *(float4*)&out[(size_t)n * F_OUT + c] = o0;
    *(float4*)&out[(size_t)n * F_OUT + c + 4] = o1;
  }
}

// ---------------- launch ----------------

extern "C" void kernel_launch(void* const* d_in, const int* in_sizes, int n_in,
                              void* d_out, int out_size, void* d_ws, size_t ws_size,
                              hipStream_t stream) {
  const float* X   = (const float*)d_in[0];
  const int*   EI  = (const int*)d_in[1];
  const float* W1  = (const float*)d_in[2];
  const float* a1s = (const float*)d_in[3];
  const float* a1d = (const float*)d_in[4];
  const float* b1  = (const float*)d_in[5];
  const float* W2  = (const float*)d_in[6];
  const float* a2s = (const float*)d_in[7];
  const float* a2d = (const float*)d_in[8];
  const float* b2  = (const float*)d_in[9];
  float* out = (float*)d_out;

  char* ws = (char*)d_ws;
  size_t off = 0;
  auto alloc = [&](size_t bytes) -> void* {
    void* p = ws + off;
    off += (bytes + 255) & ~(size_t)255;
    return p;
  };
  // zero-init block first (single memset)
  int* bcnt       = (int*)alloc((size_t)NBUCK * BPAD * 4);
  int* bfill      = (int*)alloc((size_t)NBUCK * BPAD * 4);
  float* ALS2     = (float*)alloc((size_t)N_NODES * 4);
  float* ALD2     = (float*)alloc((size_t)N_NODES * 4);
  size_t zero_span = off;
  int* boff       = (int*)alloc((size_t)(NBUCK + 1) * 4);
  int* rowptr     = (int*)alloc((size_t)(N_NODES + 1) * 4);
  int* colsrc     = (int*)alloc((size_t)NET * 4);
  int2* pairs     = (int2*)alloc((size_t)NET * 8);
  ushort_t* W1t   = (ushort_t*)alloc((size_t)C1 * F_IN * 2);
  ushort_t* W2t   = (ushort_t*)alloc((size_t)F_OUT * C1 * 2);
  schar_t* H1q    = (schar_t*)alloc((size_t)N_NODES * C1);        // 12.8MB int8
  float* SC1      = (float*)alloc((size_t)N_NODES * HEADS * 4);
  float* SC2      = (float*)alloc((size_t)N_NODES * 2 * 4);
  float* ALS1     = (float*)alloc((size_t)N_NODES * HEADS * 4);
  float* ALD1     = (float*)alloc((size_t)N_NODES * HEADS * 4);
  ushort_t* X2b   = (ushort_t*)alloc((size_t)N_NODES * C1 * 2);
  schar_t* H2q = H1q;  // H1 dead after agg1; layer-2 int8 table 6.4MB <= 12.8MB

  hipMemsetAsync(ws, 0, zero_span, stream);

  // K1: bucket histogram + weight transposes (independent, fused)
  setup_fused<<<CNT_BLOCKS + TRN_BLOCKS, 256, 0, stream>>>(EI, bcnt, W1, W1t, W2, W2t);
  // K2: bucket offsets
  scan_buckets<<<1, 1024, 0, stream>>>(bcnt, boff);
  // K3: gemm1 (needs W1t) + block-owned bucket scatter (needs boff) — independent, fused
  gemm1_plus_scatter<<<GEMM1_BLOCKS + SCAT_BLOCKS, 256, 0, stream>>>(
      X, W1t, H1q, SC1, a1s, a1d, ALS1, ALD1, EI, boff, bfill, pairs);
  // K4: per-bucket CSR finalize
  build_csr<<<NBUCK, 256, 0, stream>>>(pairs, boff, rowptr, colsrc);
  // K5: layer-1 aggregation
  agg1<<<(N_NODES + 3) / 4, 256, 0, stream>>>(rowptr, colsrc, H1q, SC1, ALS1, ALD1, b1, X2b);
  // K6: layer-2 GEMM (A = bf16 X2; C = int8 + 2 scales/node)
  {
    dim3 grid(F_OUT / 128, (N_NODES + 127) / 128);
    gemm_mfma<C1, F_OUT, 2, 2, ushort_t, schar_t><<<grid, 256, 0, stream>>>(
        X2b, W2t, H2q, SC2, a2s, a2d, ALS2, ALD2);
  }
  // K7: layer-2 aggregation -> output
  agg2<<<(N_NODES + 3) / 4, 256, 0, stream>>>(rowptr, colsrc, H2q, SC2, ALS2, ALD2, b2, out);
}

// Round 19
// 168.789 us; speedup vs baseline: 1.1547x; 1.0003x over previous
//
#include <hip/hip_runtime.h>
#include <math.h>

#define N_NODES 50000
#define F_IN    128
#define HIDC    64
#define HEADS   4
#define C1      (HEADS*HIDC)   // 256
#define F_OUT   128
#define NE      800000
#define NET     (NE + N_NODES) // 850000 edges incl self-loops
#define NEG_SLOPE 0.2f

#define NPB   49               // nodes per bucket
#define NBUCK 1021             // ceil(N_NODES / NPB)
#define BPAD  16               // counter padding (ints): 1 counter per 64B line
#define K4CAP 2048             // build_csr LDS staging cap (mean 833)
#define SCHUNK 8192            // edges per scatter chunk (1024-thread blocks)
#define CNT_BLOCKS 128
#define TRN_ELEMS (F_IN * C1 + C1 * F_OUT)      // 65536
#define TRN_BLOCKS (TRN_ELEMS / 256)            // 256
#define CASTX_BLOCKS (N_NODES * F_IN / 8 / 256) // 3125

typedef unsigned short ushort_t;
typedef signed char    schar_t;
typedef __attribute__((ext_vector_type(8))) short bf16x8;
typedef __attribute__((ext_vector_type(8))) unsigned short us8;
typedef __attribute__((ext_vector_type(4))) float f32x4;

__device__ __forceinline__ float b2f(ushort_t x) {
  return __uint_as_float(((unsigned int)x) << 16);
}
__device__ __forceinline__ ushort_t f2bf(float f) {  // RNE, no NaN expected
  unsigned int u = __float_as_uint(f);
  return (ushort_t)((u + 0x7fffu + ((u >> 16) & 1u)) >> 16);
}

// int8 x8 decode: wsc = w * scale folded; denominator uses raw w.
__device__ __forceinline__ void fma8q(float wsc, uint2 vv, float* a) {
  int x = (int)vv.x, y = (int)vv.y;
  a[0] = fmaf(wsc, (float)(schar_t)(x),        a[0]);
  a[1] = fmaf(wsc, (float)(schar_t)(x >> 8),   a[1]);
  a[2] = fmaf(wsc, (float)(schar_t)(x >> 16),  a[2]);
  a[3] = fmaf(wsc, (float)(x >> 24),           a[3]);
  a[4] = fmaf(wsc, (float)(schar_t)(y),        a[4]);
  a[5] = fmaf(wsc, (float)(schar_t)(y >> 8),   a[5]);
  a[6] = fmaf(wsc, (float)(schar_t)(y >> 16),  a[6]);
  a[7] = fmaf(wsc, (float)(y >> 24),           a[7]);
}

__device__ __forceinline__ us8 pack8(const float* p) {
  float4 f0 = *(const float4*)p;
  float4 f1 = *(const float4*)(p + 4);
  us8 o;
  o[0] = f2bf(f0.x); o[1] = f2bf(f0.y); o[2] = f2bf(f0.z); o[3] = f2bf(f0.w);
  o[4] = f2bf(f1.x); o[5] = f2bf(f1.y); o[6] = f2bf(f1.z); o[7] = f2bf(f1.w);
  return o;
}

// ---------------- K1: fused bucket_count + weight transposes + X cast ----------------

__global__ __launch_bounds__(256) void setup_fused(const int* __restrict__ ei,
                                                   int* __restrict__ bcnt,
                                                   const float* __restrict__ W1,
                                                   ushort_t* __restrict__ W1t,
                                                   const float* __restrict__ W2,
                                                   ushort_t* __restrict__ W2t,
                                                   const float* __restrict__ X,
                                                   ushort_t* __restrict__ Xb) {
  __shared__ int hist[NBUCK];
  int bid = blockIdx.x;
  if (bid < CNT_BLOCKS) {
    for (int i = threadIdx.x; i < NBUCK; i += 256) hist[i] = 0;
    __syncthreads();
    int stride = CNT_BLOCKS * 256;
    for (int e = bid * 256 + threadIdx.x; e < NET; e += stride) {
      int d = (e < NE) ? ei[NE + e] : (e - NE);
      atomicAdd(&hist[d / NPB], 1);
    }
    __syncthreads();
    for (int i = threadIdx.x; i < NBUCK; i += 256)
      if (hist[i]) atomicAdd(&bcnt[i * BPAD], hist[i]);
  } else if (bid < CNT_BLOCKS + TRN_BLOCKS) {
    int idx = (bid - CNT_BLOCKS) * 256 + threadIdx.x;
    if (idx < F_IN * C1) {
      int k = idx / C1, n = idx - k * C1;
      W1t[(size_t)n * F_IN + k] = f2bf(W1[idx]);
    } else {
      int j = idx - F_IN * C1;
      int k = j / F_OUT, n = j - k * F_OUT;
      W2t[(size_t)n * C1 + k] = f2bf(W2[j]);
    }
  } else {
    int seg = (bid - CNT_BLOCKS - TRN_BLOCKS) * 256 + threadIdx.x;  // one us8 per thread
    if (seg * 8 < N_NODES * F_IN)
      *(us8*)&Xb[(size_t)seg * 8] = pack8(&X[(size_t)seg * 8]);
  }
}

__global__ __launch_bounds__(1024) void scan_buckets(const int* __restrict__ bcnt,
                                                     int* __restrict__ boff) {
  __shared__ int sh[1024];
  int t = threadIdx.x;
  sh[t] = (t < NBUCK) ? bcnt[t * BPAD] : 0;
  __syncthreads();
#pragma unroll
  for (int off = 1; off < 1024; off <<= 1) {
    int u = (t >= off) ? sh[t - off] : 0;
    __syncthreads();
    sh[t] += u;
    __syncthreads();
  }
  if (t < NBUCK) boff[t + 1] = sh[t];
  if (t == 0) boff[0] = 0;
}

// Block-owned contiguous runs (1024 threads — round-15 proven config):
// every 64B pairs-line written by ONE block on ONE XCD.
__global__ __launch_bounds__(1024) void bucket_scatter_blocked(const int* __restrict__ ei,
                                                               const int* __restrict__ boff,
                                                               int* __restrict__ bfill,
                                                               int2* __restrict__ pairs) {
  __shared__ int hist[NBUCK];
  __shared__ int gbase[NBUCK];
  __shared__ int fill[NBUCK];
  int c0 = blockIdx.x * SCHUNK;
  int cend = min(c0 + SCHUNK, NET);
  for (int i = threadIdx.x; i < NBUCK; i += 1024) { hist[i] = 0; fill[i] = 0; }
  __syncthreads();
  for (int e = c0 + threadIdx.x; e < cend; e += 1024) {
    int d = (e < NE) ? ei[NE + e] : (e - NE);
    atomicAdd(&hist[d / NPB], 1);
  }
  __syncthreads();
  for (int i = threadIdx.x; i < NBUCK; i += 1024)
    if (hist[i]) gbase[i] = boff[i] + atomicAdd(&bfill[i * BPAD], hist[i]);
  __syncthreads();
  for (int e = c0 + threadIdx.x; e < cend; e += 1024) {
    int s, d;
    if (e < NE) { s = ei[e]; d = ei[NE + e]; }
    else        { s = e - NE; d = s; }
    int b = d / NPB;
    int lpos = atomicAdd(&fill[b], 1);
    pairs[gbase[b] + lpos] = make_int2(s, d);
  }
}

__global__ __launch_bounds__(256) void build_csr(const int2* __restrict__ pairs,
                                                 const int* __restrict__ boff,
                                                 int* __restrict__ rowptr,
                                                 int* __restrict__ colsrc) {
  __shared__ int cnt[NPB];
  __shared__ int loc[NPB + 1];
  __shared__ int2 buf[K4CAP];
  int b = blockIdx.x, t = threadIdx.x;
  int p0 = boff[b], p1 = boff[b + 1];
  int m = p1 - p0;
  int n0 = b * NPB;
  int nn = min(NPB, N_NODES - n0);
  for (int i = t; i < NPB; i += 256) cnt[i] = 0;
  __syncthreads();
  bool inlds = (m <= K4CAP);
  for (int i = t; i < m; i += 256) {
    int2 p = pairs[p0 + i];
    if (inlds) buf[i] = p;
    atomicAdd(&cnt[p.y - n0], 1);
  }
  __syncthreads();
  if (t == 0) {
    int run = 0;
#pragma unroll 1
    for (int j = 0; j < nn; ++j) { loc[j] = run; run += cnt[j]; }
    loc[nn] = run;
  }
  __syncthreads();
  for (int j = t; j < nn; j += 256) rowptr[n0 + j] = p0 + loc[j];
  if (t == 0 && n0 + nn == N_NODES) rowptr[N_NODES] = NET;
  for (int i = t; i < NPB; i += 256) cnt[i] = 0;
  __syncthreads();
  for (int i = t; i < m; i += 256) {
    int2 p = inlds ? buf[i] : pairs[p0 + i];
    int j = p.y - n0;
    int pos = atomicAdd(&cnt[j], 1);
    colsrc[p0 + loc[j] + pos] = p.x;
  }
}

// ---------------- MFMA bf16 GEMM with fused AL-logit epilogue ----------------
// CT=schar_t: int8 C + per-64ch scale (stride SCST/node). CT=ushort_t: bf16 C.

#define BKS 64
#define LDT 72

template<int K, int NCOL, int AL_MODE, int SCST, typename CT>
__global__ __launch_bounds__(256) void gemm_mfma(const ushort_t* __restrict__ A,
                                                 const ushort_t* __restrict__ Bt,
                                                 CT* __restrict__ C,
                                                 float* __restrict__ scales,
                                                 const float* __restrict__ a_s,
                                                 const float* __restrict__ a_d,
                                                 float* __restrict__ als,
                                                 float* __restrict__ ald) {
  __shared__ __align__(16) char smem[2 * 128 * LDT * 2];
  ushort_t (*Asl)[LDT] = (ushort_t(*)[LDT])smem;
  ushort_t (*Bsl)[LDT] = (ushort_t(*)[LDT])(smem + 128 * LDT * 2);

  const int tid = threadIdx.x;
  const int lane = tid & 63;
  const int wave = tid >> 6;
  const int wr = wave >> 1, wc = wave & 1;
  const int row0 = blockIdx.y * 128;
  const int col0 = blockIdx.x * 128;
  const int l15 = lane & 15, l4 = lane >> 4;

  f32x4 acc[4][4] = {};

  for (int k0 = 0; k0 < K; k0 += BKS) {
#pragma unroll
    for (int i = 0; i < 4; ++i) {
      int seg = tid + i * 256;
      int row = seg >> 3, kq = (seg & 7) * 8;
      int arow = row0 + row;
      us8 v = {0, 0, 0, 0, 0, 0, 0, 0};
      if (arow < N_NODES) v = *(const us8*)&A[(size_t)arow * K + k0 + kq];
      *(us8*)&Asl[row][kq] = v;
    }
#pragma unroll
    for (int i = 0; i < 4; ++i) {
      int seg = tid + i * 256;
      int row = seg >> 3, kq = (seg & 7) * 8;
      us8 v = *(const us8*)&Bt[(size_t)(col0 + row) * K + k0 + kq];
      *(us8*)&Bsl[row][kq] = v;
    }
    __syncthreads();
#pragma unroll
    for (int kk = 0; kk < BKS; kk += 32) {
      bf16x8 af[4], bfr[4];
#pragma unroll
      for (int mi = 0; mi < 4; ++mi)
        af[mi] = *(const bf16x8*)&Asl[wr * 64 + mi * 16 + l15][kk + l4 * 8];
#pragma unroll
      for (int ni = 0; ni < 4; ++ni)
        bfr[ni] = *(const bf16x8*)&Bsl[wc * 64 + ni * 16 + l15][kk + l4 * 8];
#pragma unroll
      for (int mi = 0; mi < 4; ++mi)
#pragma unroll
        for (int ni = 0; ni < 4; ++ni)
          acc[mi][ni] = __builtin_amdgcn_mfma_f32_16x16x32_bf16(af[mi], bfr[ni], acc[mi][ni], 0, 0, 0);
    }
    __syncthreads();
  }

  // ---- fused attention-logit dots ----
  {
    const int albase = (AL_MODE == 1 ? col0 : 0) + wc * 64;
    float asv[4], adv[4];
#pragma unroll
    for (int ni = 0; ni < 4; ++ni) {
      asv[ni] = a_s[albase + ni * 16 + l15];
      adv[ni] = a_d[albase + ni * 16 + l15];
    }
#pragma unroll
    for (int mi = 0; mi < 4; ++mi) {
      float ps[4], pd[4];
#pragma unroll
      for (int r = 0; r < 4; ++r) {
        ps[r] = acc[mi][0][r] * asv[0] + acc[mi][1][r] * asv[1] +
                acc[mi][2][r] * asv[2] + acc[mi][3][r] * asv[3];
        pd[r] = acc[mi][0][r] * adv[0] + acc[mi][1][r] * adv[1] +
                acc[mi][2][r] * adv[2] + acc[mi][3][r] * adv[3];
      }
#pragma unroll
      for (int m = 1; m < 16; m <<= 1) {
#pragma unroll
        for (int r = 0; r < 4; ++r) {
          ps[r] += __shfl_xor(ps[r], m, 64);
          pd[r] += __shfl_xor(pd[r], m, 64);
        }
      }
      if (l15 == 0) {
#pragma unroll
        for (int r = 0; r < 4; ++r) {
          int row = row0 + wr * 64 + mi * 16 + l4 * 4 + r;
          if (row < N_NODES) {
            if (AL_MODE == 1) {
              int h = albase >> 6;
              als[row * 4 + h] = ps[r];
              ald[row * 4 + h] = pd[r];
            } else {
              atomicAdd(&als[row], ps[r]);
              atomicAdd(&ald[row], pd[r]);
            }
          }
        }
      }
    }
  }

  // ---- C epilogue: acc -> LDS bf16 bounce -> global (int8+scale or bf16) ----
  {
    ushort_t (*Ep)[136] = (ushort_t(*)[136])smem;
#pragma unroll
    for (int mi = 0; mi < 4; ++mi)
#pragma unroll
      for (int ni = 0; ni < 4; ++ni)
#pragma unroll
        for (int r = 0; r < 4; ++r)
          Ep[wr * 64 + mi * 16 + l4 * 4 + r][wc * 64 + ni * 16 + l15] = f2bf(acc[mi][ni][r]);
    __syncthreads();
    int row = tid >> 1, half = tid & 1;
    int grow = row0 + row;
    if (grow < N_NODES) {
      if constexpr (sizeof(CT) == 1) {
        float vals[64];
        float amax = 0.f;
#pragma unroll
        for (int i = 0; i < 8; ++i) {
          us8 v = *(const us8*)&Ep[row][half * 64 + i * 8];
#pragma unroll
          for (int j = 0; j < 8; ++j) {
            float f = b2f((ushort_t)v[j]);
            vals[i * 8 + j] = f;
            amax = fmaxf(amax, fabsf(f));
          }
        }
        float inv = amax > 0.f ? 127.f / amax : 0.f;
        scales[grow * SCST + (col0 >> 6) + half] = amax * (1.f / 127.f);
        schar_t ob[64];
#pragma unroll
        for (int i = 0; i < 64; ++i)
          ob[i] = (schar_t)(int)rintf(vals[i] * inv);
#pragma unroll
        for (int i = 0; i < 4; ++i)
          *(us8*)&C[(size_t)grow * NCOL + col0 + half * 64 + i * 16] =
              *(const us8*)&ob[i * 16];
      } else {
#pragma unroll
        for (int i = 0; i < 8; ++i)
          *(us8*)&C[(size_t)grow * NCOL + col0 + half * 64 + i * 8] =
              *(const us8*)&Ep[row][half * 64 + i * 8];
      }
    }
  }
}

// ---------------- fused softmax + gather aggregation (all int8) ----------------

// layer1: half-wave (32 lanes x 8B) per edge; 2 edges/wave, unroll 4 -> 8 in flight.
__global__ __launch_bounds__(256) void agg1(const int* __restrict__ rowptr,
                                            const int* __restrict__ colsrc,
                                            const schar_t* __restrict__ Hq,
                                            const float* __restrict__ Sc,
                                            const float* __restrict__ als,
                                            const float* __restrict__ ald,
                                            const float* __restrict__ b1,
                                            ushort_t* __restrict__ X2b) {
  int wave = threadIdx.x >> 6, lane = threadIdx.x & 63;
  int n = blockIdx.x * 4 + wave;
  if (n >= N_NODES) return;
  int half = lane >> 5, li = lane & 31, h = li >> 3;
  float ad = ald[n * 4 + h];
  int beg = rowptr[n], end = rowptr[n + 1];
  float a[8] = {};
  float s = 0.f;
  int i = beg + half;
  for (; i + 6 < end; i += 8) {
    int s0 = colsrc[i], s1 = colsrc[i + 2], s2 = colsrc[i + 4], s3 = colsrc[i + 6];
    float sc0 = als[s0 * 4 + h] + ad;
    float sc1 = als[s1 * 4 + h] + ad;
    float sc2 = als[s2 * 4 + h] + ad;
    float sc3 = als[s3 * 4 + h] + ad;
    float q0 = Sc[s0 * 4 + h], q1 = Sc[s1 * 4 + h], q2 = Sc[s2 * 4 + h], q3 = Sc[s3 * 4 + h];
    uint2 v0 = *(const uint2*)&Hq[(size_t)s0 * C1 + li * 8];
    uint2 v1 = *(const uint2*)&Hq[(size_t)s1 * C1 + li * 8];
    uint2 v2 = *(const uint2*)&Hq[(size_t)s2 * C1 + li * 8];
    uint2 v3 = *(const uint2*)&Hq[(size_t)s3 * C1 + li * 8];
    sc0 = sc0 > 0.f ? sc0 : NEG_SLOPE * sc0;
    sc1 = sc1 > 0.f ? sc1 : NEG_SLOPE * sc1;
    sc2 = sc2 > 0.f ? sc2 : NEG_SLOPE * sc2;
    sc3 = sc3 > 0.f ? sc3 : NEG_SLOPE * sc3;
    float w0 = __expf(sc0), w1 = __expf(sc1), w2 = __expf(sc2), w3 = __expf(sc3);
    s += (w0 + w1) + (w2 + w3);
    fma8q(w0 * q0, v0, a); fma8q(w1 * q1, v1, a);
    fma8q(w2 * q2, v2, a); fma8q(w3 * q3, v3, a);
  }
  for (; i + 2 < end; i += 4) {
    int s0 = colsrc[i], s1 = colsrc[i + 2];
    float sc0 = als[s0 * 4 + h] + ad;
    float sc1 = als[s1 * 4 + h] + ad;
    float q0 = Sc[s0 * 4 + h], q1 = Sc[s1 * 4 + h];
    uint2 v0 = *(const uint2*)&Hq[(size_t)s0 * C1 + li * 8];
    uint2 v1 = *(const uint2*)&Hq[(size_t)s1 * C1 + li * 8];
    sc0 = sc0 > 0.f ? sc0 : NEG_SLOPE * sc0;
    sc1 = sc1 > 0.f ? sc1 : NEG_SLOPE * sc1;
    float w0 = __expf(sc0), w1 = __expf(sc1);
    s += w0 + w1;
    fma8q(w0 * q0, v0, a); fma8q(w1 * q1, v1, a);
  }
  for (; i < end; i += 2) {
    int s0 = colsrc[i];
    float sc0 = als[s0 * 4 + h] + ad;
    float q0 = Sc[s0 * 4 + h];
    uint2 v0 = *(const uint2*)&Hq[(size_t)s0 * C1 + li * 8];
    sc0 = sc0 > 0.f ? sc0 : NEG_SLOPE * sc0;
    float w0 = __expf(sc0);
    s += w0;
    fma8q(w0 * q0, v0, a);
  }
#pragma unroll
  for (int j = 0; j < 8; ++j) a[j] += __shfl_xor(a[j], 32, 64);
  s += __shfl_xor(s, 32, 64);
  if (lane < 32) {
    float si = 1.f / s;
    int c = li * 8;
    ushort_t o[8];
#pragma unroll
    for (int j = 0; j < 8; ++j)
      o[j] = f2bf(fmaxf(a[j] * si + b1[c + j], 0.f));
    *(us8*)&X2b[(size_t)n * C1 + c] = *(const us8*)o;
  }
}

// layer2 int8: quarter-wave (16 lanes x 8B = 128 ch) per edge; 4 edges/wave,
// unroll 2 -> 8 in flight.
__global__ __launch_bounds__(256) void agg2(const int* __restrict__ rowptr,
                                            const int* __restrict__ colsrc,
                                            const schar_t* __restrict__ Hq,
                                            const float* __restrict__ Sc,
                                            const float* __restrict__ als,
                                            const float* __restrict__ ald,
                                            const float* __restrict__ b2,
                                            float* __restrict__ out) {
  int wave = threadIdx.x >> 6, lane = threadIdx.x & 63;
  int n = blockIdx.x * 4 + wave;
  if (n >= N_NODES) return;
  int quarter = lane >> 4, li = lane & 15;
  int hb = li >> 3;
  float ad = ald[n];
  int beg = rowptr[n], end = rowptr[n + 1];
  float a[8] = {};
  float s = 0.f;
  int i = beg + quarter;
  for (; i + 4 < end; i += 8) {
    int s0 = colsrc[i], s1 = colsrc[i + 4];
    float sc0 = als[s0] + ad;
    float sc1 = als[s1] + ad;
    float q0 = Sc[s0 * 2 + hb], q1 = Sc[s1 * 2 + hb];
    uint2 v0 = *(const uint2*)&Hq[(size_t)s0 * F_OUT + li * 8];
    uint2 v1 = *(const uint2*)&Hq[(size_t)s1 * F_OUT + li * 8];
    sc0 = sc0 > 0.f ? sc0 : NEG_SLOPE * sc0;
    sc1 = sc1 > 0.f ? sc1 : NEG_SLOPE * sc1;
    float w0 = __expf(sc0), w1 = __expf(sc1);
    s += w0 + w1;
    fma8q(w0 * q0, v0, a); fma8q(w1 * q1, v1, a);
  }
  for (; i < end; i += 4) {
    int s0 = colsrc[i];
    float sc0 = als[s0] + ad;
    float q0 = Sc[s0 * 2 + hb];
    uint2 v0 = *(const uint2*)&Hq[(size_t)s0 * F_OUT + li * 8];
    sc0 = sc0 > 0.f ? sc0 : NEG_SLOPE * sc0;
    float w0 = __expf(sc0);
    s += w0;
    fma8q(w0 * q0, v0, a);
  }
#pragma unroll
  for (int j = 0; j < 8; ++j) a[j] += __shfl_xor(a[j], 16, 64);
#pragma unroll
  for (int j = 0; j < 8; ++j) a[j] += __shfl_xor(a[j], 32, 64);
  s += __shfl_xor(s, 16, 64);
  s += __shfl_xor(s, 32, 64);
  if (lane < 16) {
    float si = 1.f / s;
    int c = li * 8;
    float4 o0, o1;
    o0.x = a[0] * si + b2[c + 0]; o0.y = a[1] * si + b2[c + 1];
    o0.z = a[2] * si + b2[c + 2]; o0.w = a[3] * si + b2[c + 3];
    o1.x = a[4] * si + b2[c + 4]; o1.y = a[5] * si + b2[c + 5];
    o1.z = a[6] * si + b2[c + 6]; o1.w = a[7] * si + b2[c + 7];
    *(float4*)&out[(size_t)n * F_OUT + c] = o0;
    *(float4*)&out[(size_t)n * F_OUT + c + 4] = o1;
  }
}

// ---------------- launch ----------------

extern "C" void kernel_launch(void* const* d_in, const int* in_sizes, int n_in,
                              void* d_out, int out_size, void* d_ws, size_t ws_size,
                              hipStream_t stream) {
  const float* X   = (const float*)d_in[0];
  const int*   EI  = (const int*)d_in[1];
  const float* W1  = (const float*)d_in[2];
  const float* a1s = (const float*)d_in[3];
  const float* a1d = (const float*)d_in[4];
  const float* b1  = (const float*)d_in[5];
  const float* W2  = (const float*)d_in[6];
  const float* a2s = (const float*)d_in[7];
  const float* a2d = (const float*)d_in[8];
  const float* b2  = (const float*)d_in[9];
  float* out = (float*)d_out;

  char* ws = (char*)d_ws;
  size_t off = 0;
  auto alloc = [&](size_t bytes) -> void* {
    void* p = ws + off;
    off += (bytes + 255) & ~(size_t)255;
    return p;
  };
  // zero-init block first (single memset)
  int* bcnt       = (int*)alloc((size_t)NBUCK * BPAD * 4);
  int* bfill      = (int*)alloc((size_t)NBUCK * BPAD * 4);
  float* ALS2     = (float*)alloc((size_t)N_NODES * 4);
  float* ALD2     = (float*)alloc((size_t)N_NODES * 4);
  size_t zero_span = off;
  int* boff       = (int*)alloc((size_t)(NBUCK + 1) * 4);
  int* rowptr     = (int*)alloc((size_t)(N_NODES + 1) * 4);
  int* colsrc     = (int*)alloc((size_t)NET * 4);
  int2* pairs     = (int2*)alloc((size_t)NET * 8);
  ushort_t* W1t   = (ushort_t*)alloc((size_t)C1 * F_IN * 2);
  ushort_t* W2t   = (ushort_t*)alloc((size_t)F_OUT * C1 * 2);
  ushort_t* Xb    = (ushort_t*)alloc((size_t)N_NODES * F_IN * 2);  // 12.8MB bf16
  schar_t* H1q    = (schar_t*)alloc((size_t)N_NODES * C1);         // 12.8MB int8
  float* SC1      = (float*)alloc((size_t)N_NODES * HEADS * 4);
  float* SC2      = (float*)alloc((size_t)N_NODES * 2 * 4);
  float* ALS1     = (float*)alloc((size_t)N_NODES * HEADS * 4);
  float* ALD1     = (float*)alloc((size_t)N_NODES * HEADS * 4);
  ushort_t* X2b   = (ushort_t*)alloc((size_t)N_NODES * C1 * 2);
  schar_t* H2q = H1q;  // H1 dead after agg1; layer-2 int8 table 6.4MB <= 12.8MB

  hipMemsetAsync(ws, 0, zero_span, stream);

  // K1: bucket histogram + weight transposes + X->bf16 cast (independent, fused)
  setup_fused<<<CNT_BLOCKS + TRN_BLOCKS + CASTX_BLOCKS, 256, 0, stream>>>(
      EI, bcnt, W1, W1t, W2, W2t, X, Xb);
  // K2: bucket offsets
  scan_buckets<<<1, 1024, 0, stream>>>(bcnt, boff);
  // K3: block-owned bucket scatter (1024 threads, round-15 proven config)
  bucket_scatter_blocked<<<(NET + SCHUNK - 1) / SCHUNK, 1024, 0, stream>>>(EI, boff, bfill, pairs);
  // K4: layer-1 GEMM (A = bf16 Xb; C = int8 + 4 scales/node)
  {
    dim3 grid(C1 / 128, (N_NODES + 127) / 128);
    gemm_mfma<F_IN, C1, 1, 4, schar_t><<<grid, 256, 0, stream>>>(
        Xb, W1t, H1q, SC1, a1s, a1d, ALS1, ALD1);
  }
  // K5: per-bucket CSR finalize
  build_csr<<<NBUCK, 256, 0, stream>>>(pairs, boff, rowptr, colsrc);
  // K6: layer-1 aggregation
  agg1<<<(N_NODES + 3) / 4, 256, 0, stream>>>(rowptr, colsrc, H1q, SC1, ALS1, ALD1, b1, X2b);
  // K7: layer-2 GEMM (A = bf16 X2; C = int8 + 2 scales/node)
  {
    dim3 grid(F_OUT / 128, (N_NODES + 127) / 128);
    gemm_mfma<C1, F_OUT, 2, 2, schar_t><<<grid, 256, 0, stream>>>(
        X2b, W2t, H2q, SC2, a2s, a2d, ALS2, ALD2);
  }
  // K8: layer-2 aggregation -> output
  agg2<<<(N_NODES + 3) / 4, 256, 0, stream>>>(rowptr, colsrc, H2q, SC2, ALS2, ALD2, b2, out);
}